// Round 13
// baseline (446.094 us; speedup 1.0000x reference)
//
#include <hip/hip_runtime.h>
#include <hip/hip_bf16.h>
#include <math.h>

#define GG 4096
#define PP 4096
#define HH 64
#define BB 4
#define E1N 81920
#define E2N 81920
#define FFD 512
#define BNEPS 1e-5f
#define LOG2E 1.44269504088896341f
#define QPRE (0.17677669529663687f * LOG2E)

typedef unsigned short ushort_t;
typedef unsigned int uint_t;
using sh8 = __attribute__((ext_vector_type(8))) short;
using sh4 = __attribute__((ext_vector_type(4))) short;
using f4  = __attribute__((ext_vector_type(4))) float;

struct MaskOn  { static constexpr bool v = true; };
struct MaskOff { static constexpr bool v = false; };

#if __has_builtin(__builtin_amdgcn_mfma_f32_16x16x16bf16_1k)
#define MFMA16(a, b, c) __builtin_amdgcn_mfma_f32_16x16x16bf16_1k((a), (b), (c), 0, 0, 0)
#elif __has_builtin(__builtin_amdgcn_mfma_f32_16x16x16_bf16)
#define MFMA16(a, b, c) __builtin_amdgcn_mfma_f32_16x16x16_bf16((a), (b), (c), 0, 0, 0)
#else
static __device__ inline f4 mfma16_asm(sh4 a, sh4 b, f4 c) {
    f4 d;
    asm volatile("v_mfma_f32_16x16x16_bf16 %0, %1, %2, %3"
                 : "=v"(d) : "v"(a), "v"(b), "v"(c));
    return d;
}
#define MFMA16(a, b, c) mfma16_asm((a), (b), (c))
#endif

// ---------------- workspace layout (float offsets) ----------------
#define OF_STATS   0          // 6 slots x 256 (raw sum[128] + sumsq[128])
#define OF_DEGCO   2048
#define OF_DEGGO   6144
#define OF_PSLOT   10240
#define OF_ETOT    10752
#define OF_HDC     11008
#define OF_HE      11136
#define OF_MFLAG   11264      // int: 1 if mask has any nonzero bits
// CSR sort of co-expression edges (lives in dead AGGCO region 12288..274432)
#define OF_CNT     12288      // int[4096]  edge counts per dst
#define OF_OFFS    16384      // int[4097]  CSR offsets
#define OF_WOFF    20608      // int[4096]  scatter cursors
#define OF_SSRC    24704      // int[81920] sorted src
#define OF_SNRM    106624     // f32[81920] sorted norm
#define OF_BASEIN  274432
#define OF_Y1      536576
#define OF_Y2      798720
#define OF_FLAT    1060864    // (Vf region)
#define OF_RW1     2109440    // 16384 x 128
#define OF_RW2     4206592    // 16384 x 64
#define OF_OUT     5255168    // attn split 1 partial (bf16)
#define OF_QKV     6303744    // attn split 0 partial (bf16)
// bf16 attention buffers (alias dead fp32 regions)
#define OF_QB      12288      // 8*4096*32 ushort (dead CSR region by QKV time)
#define OF_KB      (OF_QB + 524288)
#define OF_VF      OF_FLAT    // 8*64*2048 ushort (V frag-order)
// attention k-split partials
#define OF_OPA     OF_QKV
#define OF_OPB     OF_OUT
#define OF_LP      OF_RW1     // 2*8*4096
#define OF_H1      (OF_RW1 + 131072)   // bf16[16384*64] post-LN1 h1 (dead yrw1 region)
#define OPS        1048576
// FFN bf16 weights (dead FFO region)
#define OF_W1B     9449472    // 512*64 bf16
#define OF_W2B     9465856    // 64*512 bf16

__device__ inline ushort_t f2b(float f) {
    uint_t u = __builtin_bit_cast(uint_t, f);
    u += 0x7FFFu + ((u >> 16) & 1u);
    return (ushort_t)(u >> 16);
}

__device__ inline float b2f32(ushort_t u) {
    return __builtin_bit_cast(float, (uint_t)u << 16);
}

__device__ inline void gld16(const void* gptr, void* lptr) {
    __builtin_amdgcn_global_load_lds(
        (const __attribute__((address_space(1))) uint_t*)gptr,
        (__attribute__((address_space(3))) uint_t*)lptr, 16, 0, 0);
}

// ================= device sub-kernels =================
__device__ void dev_vae_he(int bid, const float* __restrict__ x, const float* __restrict__ W,
                           const float* __restrict__ bias, float* he, float* sh) {
    int b = bid >> 5, i = bid & 31;
    float s = 0.f;
    for (int g = threadIdx.x; g < 4096; g += 256) s += x[b * 4096 + g] * W[i * 4096 + g];
    sh[threadIdx.x] = s;
    __syncthreads();
    for (int o = 128; o > 0; o >>= 1) {
        if (threadIdx.x < o) sh[threadIdx.x] += sh[threadIdx.x + o];
        __syncthreads();
    }
    if (threadIdx.x == 0) he[b * 32 + i] = fmaxf(sh[0] + bias[i], 0.f);
}

__device__ void dev_vae_mid(const float* __restrict__ he,
                            const float* __restrict__ muw, const float* __restrict__ mub,
                            const float* __restrict__ lvw, const float* __restrict__ lvb,
                            const float* __restrict__ d1w, const float* __restrict__ d1b,
                            const float* __restrict__ eps, float* hdc, float* klout, float* zs) {
    int t = threadIdx.x;
    if (t < 64) {
        int b = t >> 4, l = t & 15;
        float mu = mub[l], lv = lvb[l];
        for (int i = 0; i < 32; i++) {
            float hv = he[b * 32 + i];
            mu += hv * muw[l * 32 + i];
            lv += hv * lvw[l * 32 + i];
        }
        zs[t] = mu + eps[t] * expf(0.5f * lv);
        float kterm = 1.f + lv - mu * mu - expf(lv);
        for (int o = 32; o > 0; o >>= 1) kterm += __shfl_xor(kterm, o, 64);
        if (t == 0) klout[0] = -0.5f * kterm * 0.25f;
    }
    __syncthreads();
    if (t < 128) {
        int b = t >> 5, i = t & 31;
        float a = d1b[i];
        for (int l = 0; l < 16; l++) a += zs[b * 16 + l] * d1w[i * 16 + l];
        hdc[t] = fmaxf(a, 0.f);
    }
}

__device__ void dev_edge_deg(int bid, const int* __restrict__ ei, const float* __restrict__ w,
                             float* deg, int E, int* cnt) {
    int e = bid * 256 + threadIdx.x;
    if (e < E) {
        int d = ei[E + e];
        atomicAdd(&deg[d], w[e]);
        if (cnt) atomicAdd(&cnt[d], 1);
    }
}

__device__ void dev_cs_part(int bid, const float* __restrict__ X, int N,
                            float* sum, float* sumsq, float* sh) {
    int t = threadIdx.x;
    int col = t & 63, ro = t >> 6;
    int rows = N >> 8;
    int r0 = bid * rows;
    float s = 0.f, q = 0.f;
    for (int r = r0 + ro; r < r0 + rows; r += 4) {
        float v = X[r * 64 + col];
        s += v; q += v * v;
    }
    float* ls = sh; float* lq = sh + 256;
    ls[t] = s; lq[t] = q;
    __syncthreads();
    if (t < 64) {
        for (int j = t + 64; j < 256; j += 64) { s += ls[j]; q += lq[j]; }
        atomicAdd(&sum[t], s);
        atomicAdd(&sumsq[t], q);
    }
}

// bitwise OR-scan of mask; sets flag if any nonzero bits (conservative: -0.0 counts)
__device__ void dev_mask_scan(int bid, const float* __restrict__ mask, int* flag) {
    const uint4* m4 = (const uint4*)mask;
    const int total = (GG * GG) / 4;          // 4,194,304 uint4
    uint_t acc = 0u;
    for (int i = bid * 256 + threadIdx.x; i < total; i += 512 * 256) {
        uint4 v = m4[i];
        acc |= v.x | v.y | v.z | v.w;
    }
    if (acc) atomicOr(flag, 1);
}

// scatter co-edges into CSR order (pos via cursor atomic; 4B traffic only)
__device__ void dev_scatter(int bid, const int* __restrict__ ei, const float* __restrict__ w,
                            const float* __restrict__ deg,
                            int* woff, int* ssrc, float* snrm) {
    int e = bid * 256 + threadIdx.x;
    if (e >= E1N) return;
    int src = ei[e], dst = ei[E1N + e];
    float nrm = rsqrtf(deg[dst] + 1.f) * w[e] * rsqrtf(deg[src] + 1.f);
    int pos = atomicAdd(&woff[dst], 1);
    ssrc[pos] = src;
    snrm[pos] = nrm;
}

// wave-cooperative pert-edge accumulation (matches are rare: ballot + broadcast)
__device__ void dev_pert_edges(int bid, const int* __restrict__ pidx, const int* __restrict__ ei,
                               const float* __restrict__ w, const float* __restrict__ deg,
                               const float* __restrict__ tbl, float* pslot) {
    int e = bid * 256 + threadIdx.x;
    int lane = threadIdx.x & 63;
    bool valid = e < E2N;
    int dst = valid ? ei[E2N + e] : -1;
    int hit = 0;
    #pragma unroll
    for (int s = 0; s < 8; s++) hit |= (pidx[s] == dst) ? (1 << s) : 0;
    if (__ballot(hit != 0) == 0) return;          // whole-wave fast exit
    int src = valid ? ei[e] : 0;
    float nrm = 0.f;
    if (hit) nrm = rsqrtf(deg[dst] + 1.f) * w[e] * rsqrtf(deg[src] + 1.f);
    for (int s = 0; s < 8; s++) {
        unsigned long long m = __ballot((hit >> s) & 1);
        while (m) {
            int l = __builtin_ctzll(m);
            m &= m - 1;
            int es = __shfl(src, l, 64);
            float en = __shfl(nrm, l, 64);
            atomicAdd(&pslot[s * 64 + lane], en * tbl[es * 64 + lane]);
        }
    }
}

// base combine with fused CSR gather (no agg buffer, no atomics)
__device__ void dev_base_combine(int bid, const float* __restrict__ gene_emb,
                                 const int* __restrict__ off, const int* __restrict__ ssrc,
                                 const float* __restrict__ snrm,
                                 const float* __restrict__ emb_pos,
                                 const float* __restrict__ deg,
                                 const float* __restrict__ W, const float* __restrict__ bias,
                                 const float* __restrict__ bsum, const float* __restrict__ bsq,
                                 const float* __restrict__ bg, const float* __restrict__ bb,
                                 float* out, float* sh) {
    float* Wt = sh;            // [64][65]
    float* a = sh + 4160;      // [4][64]
    int t = threadIdx.x;
    for (int i = t; i < 4096; i += 256) Wt[(i & 63) * 65 + (i >> 6)] = W[i];
    int rr = t >> 6, h = t & 63;
    int g = bid * 4 + rr;
    float acc = emb_pos[g * 64 + h] / (deg[g] + 1.f);   // self-loop term
    int e = off[g];
    const int e1 = off[g + 1];
    for (; e + 4 <= e1; e += 4) {
        int s0 = ssrc[e], s1 = ssrc[e + 1], s2 = ssrc[e + 2], s3 = ssrc[e + 3];
        float n0 = snrm[e], n1 = snrm[e + 1], n2 = snrm[e + 2], n3 = snrm[e + 3];
        acc += n0 * emb_pos[s0 * 64 + h];
        acc += n1 * emb_pos[s1 * 64 + h];
        acc += n2 * emb_pos[s2 * 64 + h];
        acc += n3 * emb_pos[s3 * 64 + h];
    }
    for (; e < e1; e++) acc += snrm[e] * emb_pos[ssrc[e] * 64 + h];
    a[rr * 64 + h] = acc;
    __syncthreads();
    float y = bias[h];
    const float* ar = a + rr * 64;
    #pragma unroll 8
    for (int k = 0; k < 64; k++) y += ar[k] * Wt[k * 65 + h];
    const float invN = 1.0f / (float)GG;
    float m = bsum[h] * invN;
    float is_ = rsqrtf(bsq[h] * invN - m * m + BNEPS);
    float v = gene_emb[g * 64 + h];
    v = (v - m) * is_ * bg[h] + bb[h];
    v = fmaxf(v, 0.f);
    out[g * 64 + h] = v + 0.2f * y;
}

__device__ void dev_pert_mlp(const float* __restrict__ pslot, const int* __restrict__ pidx,
                             const float* __restrict__ deg, const float* __restrict__ tbl,
                             const float* __restrict__ gw, const float* __restrict__ gb,
                             const float* __restrict__ w1, const float* __restrict__ b1,
                             const float* __restrict__ g1, const float* __restrict__ be1,
                             const float* __restrict__ w2, const float* __restrict__ b2,
                             const float* __restrict__ g2, const float* __restrict__ be2,
                             float* etot, float* sh) {
    float* pge = sh;
    float* psum = sh + 512;
    float* y = sh + 768;
    float* mh = sh + 1024;
    float* ih = sh + 1088;
    int t = threadIdx.x;
    for (int j = t; j < 512; j += 256) {
        int s = j >> 6, h = j & 63;
        int n = pidx[s];
        float invd = 1.0f / (deg[n] + 1.f);
        float acc = gb[h];
        for (int k = 0; k < 64; k++)
            acc += (pslot[s * 64 + k] + tbl[n * 64 + k] * invd) * gw[h * 64 + k];
        pge[j] = acc;
    }
    __syncthreads();
    { int b = t >> 6, h = t & 63; psum[t] = pge[2 * b * 64 + h] + pge[(2 * b + 1) * 64 + h]; }
    __syncthreads();
    { int h = t & 63; int b = t >> 6;
      float acc = b1[h];
      for (int k = 0; k < 64; k++) acc += psum[b * 64 + k] * w1[h * 64 + k];
      y[t] = acc; }
    __syncthreads();
    if (t < 64) {
        float s = 0.f, sq = 0.f;
        for (int b = 0; b < 4; b++) { float v = y[b * 64 + t]; s += v; sq += v * v; }
        float m = s * 0.25f;
        mh[t] = m; ih[t] = rsqrtf(sq * 0.25f - m * m + BNEPS);
    }
    __syncthreads();
    { int h = t & 63;
      float v = (y[t] - mh[h]) * ih[h] * g1[h] + be1[h];
      psum[t] = fmaxf(v, 0.f); }
    __syncthreads();
    { int h = t & 63; int b = t >> 6;
      float acc = b2[h];
      for (int k = 0; k < 64; k++) acc += psum[b * 64 + k] * w2[h * 64 + k];
      y[t] = acc; }
    __syncthreads();
    if (t < 64) {
        float s = 0.f, sq = 0.f;
        for (int b = 0; b < 4; b++) { float v = y[b * 64 + t]; s += v; sq += v * v; }
        float m = s * 0.25f;
        mh[t] = m; ih[t] = rsqrtf(sq * 0.25f - m * m + BNEPS);
    }
    __syncthreads();
    { int h = t & 63;
      etot[t] = (y[t] - mh[h]) * ih[h] * g2[h] + be2[h]; }
}

// ================= fat kernels =================
// K12: edge_deg co+cnt(320) | edge_deg go(320) | cs_part gene_emb(256) | vae_he(128)
//      | W->bf16(256) | mask_scan(512)
__global__ void k_fat12(float* ws, const int* __restrict__ ei_co, const float* __restrict__ w_co,
                        const int* __restrict__ ei_go, const float* __restrict__ w_go,
                        const float* __restrict__ gene_emb, const float* __restrict__ x,
                        const float* __restrict__ ve1_w, const float* __restrict__ ve1_b,
                        const float* __restrict__ ff1_w, const float* __restrict__ ff2_w,
                        const float* __restrict__ mask) {
    __shared__ float sh[512];
    int bid = blockIdx.x;
    if (bid < 320) dev_edge_deg(bid, ei_co, w_co, ws + OF_DEGCO, E1N, (int*)(ws + OF_CNT));
    else if (bid < 640) dev_edge_deg(bid - 320, ei_go, w_go, ws + OF_DEGGO, E2N, nullptr);
    else if (bid < 896) dev_cs_part(bid - 640, gene_emb, GG, ws + OF_STATS, ws + OF_STATS + 128, sh);
    else if (bid < 1024) dev_vae_he(bid - 896, x, ve1_w, ve1_b, ws + OF_HE, sh);
    else if (bid < 1280) {
        int i = (bid - 1024) * 256 + threadIdx.x;   // 256 blocks -> 65536
        ushort_t* W1b = (ushort_t*)(ws + OF_W1B);
        ushort_t* W2b = (ushort_t*)(ws + OF_W2B);
        if (i < 32768) W1b[i] = f2b(ff1_w[i]);
        else W2b[i - 32768] = f2b(ff2_w[i - 32768]);
    } else dev_mask_scan(bid - 1280, mask, (int*)(ws + OF_MFLAG));
}

// KSCAN: exclusive prefix sum of cnt[4096] -> off[4097] (+ mutable cursor copy)
__global__ void k_scan(float* ws) {
    int* cnt = (int*)(ws + OF_CNT);
    int* off = (int*)(ws + OF_OFFS);
    int* woff = (int*)(ws + OF_WOFF);
    __shared__ int part[256];
    const int t = threadIdx.x;
    int loc[16];
    int s = 0;
    #pragma unroll
    for (int i = 0; i < 16; i++) { loc[i] = s; s += cnt[t * 16 + i]; }
    part[t] = s;
    __syncthreads();
    for (int o = 1; o < 256; o <<= 1) {
        int v = (t >= o) ? part[t - o] : 0;
        __syncthreads();
        part[t] += v;
        __syncthreads();
    }
    int prev = (t == 0) ? 0 : part[t - 1];
    #pragma unroll
    for (int i = 0; i < 16; i++) {
        int o = prev + loc[i];
        off[t * 16 + i] = o;
        woff[t * 16 + i] = o;
    }
    if (t == 255) off[4096] = part[255];
}

// K3: scatter(320) | pert_edges(320) | vae_mid(1)
__global__ void k_fat3(float* ws, const int* __restrict__ ei_co, const float* __restrict__ w_co,
                       const int* __restrict__ pidx,
                       const int* __restrict__ ei_go, const float* __restrict__ w_go,
                       const float* __restrict__ pert_tbl,
                       const float* __restrict__ vmu_w, const float* __restrict__ vmu_b,
                       const float* __restrict__ vlv_w, const float* __restrict__ vlv_b,
                       const float* __restrict__ vd1_w, const float* __restrict__ vd1_b,
                       const float* __restrict__ veps, float* klout) {
    __shared__ float sh[512];
    int bid = blockIdx.x;
    if (bid < 320)
        dev_scatter(bid, ei_co, w_co, ws + OF_DEGCO,
                    (int*)(ws + OF_WOFF), (int*)(ws + OF_SSRC), ws + OF_SNRM);
    else if (bid < 640)
        dev_pert_edges(bid - 320, pidx, ei_go, w_go, ws + OF_DEGGO, pert_tbl, ws + OF_PSLOT);
    else dev_vae_mid(ws + OF_HE, vmu_w, vmu_b, vlv_w, vlv_b, vd1_w, vd1_b, veps,
                     ws + OF_HDC, klout, sh);
}

// K4: base_combine+gather(1024) | pert_mlp(1)
__global__ void k_fat4(float* ws, const float* __restrict__ gene_emb,
                       const float* __restrict__ emb_pos,
                       const float* __restrict__ sg_co_w, const float* __restrict__ sg_co_b,
                       const float* __restrict__ bn_emb_g, const float* __restrict__ bn_emb_b,
                       const int* __restrict__ pidx, const float* __restrict__ pert_tbl,
                       const float* __restrict__ gw, const float* __restrict__ gb,
                       const float* __restrict__ w1, const float* __restrict__ b1,
                       const float* __restrict__ g1, const float* __restrict__ be1,
                       const float* __restrict__ w2, const float* __restrict__ b2,
                       const float* __restrict__ g2, const float* __restrict__ be2) {
    __shared__ float sh[4416];
    int bid = blockIdx.x;
    if (bid < 1024)
        dev_base_combine(bid, gene_emb, (const int*)(ws + OF_OFFS),
                         (const int*)(ws + OF_SSRC), ws + OF_SNRM,
                         emb_pos, ws + OF_DEGCO,
                         sg_co_w, sg_co_b, ws + OF_STATS, ws + OF_STATS + 128,
                         bn_emb_g, bn_emb_b, ws + OF_BASEIN, sh);
    else
        dev_pert_mlp(ws + OF_PSLOT, pidx, ws + OF_DEGGO, pert_tbl, gw, gb,
                     w1, b1, g1, be1, w2, b2, g2, be2, ws + OF_ETOT, sh);
}

// ================= gemm64 (fp32, etv/rw chain) =================
__launch_bounds__(256)
__global__ void k_gemm64(const float* __restrict__ X, const float* __restrict__ W,
                         const float* __restrict__ bias, float* __restrict__ Y,
                         int Cin, int Cout,
                         const float* __restrict__ bnsum, const float* __restrict__ bnsq,
                         const float* __restrict__ bng, const float* __restrict__ bnb,
                         float invN, int relu_in,
                         float* __restrict__ outsum, float* __restrict__ outsq) {
    __shared__ float Xs[64][66];
    __shared__ float Ws[64][66];
    __shared__ float bsc[64], bsh[64];
    const int t = threadIdx.x;
    const int row0 = blockIdx.x * 64, cb = blockIdx.y * 64;
    const int tx = t & 15, ty = t >> 4;
    const int c0 = tx * 4, r0 = ty * 4;
    float acc[4][4];
    #pragma unroll
    for (int j = 0; j < 4; j++)
        #pragma unroll
        for (int i = 0; i < 4; i++) acc[j][i] = 0.f;

    for (int k0 = 0; k0 < Cin; k0 += 64) {
        __syncthreads();
        if (t < 64) {
            float sc = 1.f, sh = 0.f;
            if (bnsum) {
                int c = k0 + t;
                float m = bnsum[c] * invN;
                float is_ = rsqrtf(bnsq[c] * invN - m * m + BNEPS);
                sc = is_ * bng[c]; sh = bnb[c] - m * sc;
            }
            bsc[t] = sc; bsh[t] = sh;
        }
        __syncthreads();
        for (int i = t; i < 1024; i += 256) {
            int r = i >> 4, kq = (i & 15) * 4;
            float4 v = *(const float4*)&X[(size_t)(row0 + r) * Cin + k0 + kq];
            float e0 = v.x * bsc[kq] + bsh[kq];
            float e1 = v.y * bsc[kq + 1] + bsh[kq + 1];
            float e2 = v.z * bsc[kq + 2] + bsh[kq + 2];
            float e3 = v.w * bsc[kq + 3] + bsh[kq + 3];
            if (relu_in) {
                e0 = fmaxf(e0, 0.f); e1 = fmaxf(e1, 0.f);
                e2 = fmaxf(e2, 0.f); e3 = fmaxf(e3, 0.f);
            }
            Xs[r][kq] = e0; Xs[r][kq + 1] = e1; Xs[r][kq + 2] = e2; Xs[r][kq + 3] = e3;
            float4 wv = *(const float4*)&W[(size_t)(cb + r) * Cin + k0 + kq];
            Ws[r][kq] = wv.x; Ws[r][kq + 1] = wv.y; Ws[r][kq + 2] = wv.z; Ws[r][kq + 3] = wv.w;
        }
        __syncthreads();
        #pragma unroll 4
        for (int k = 0; k < 64; k += 2) {
            float2 a[4], b[4];
            #pragma unroll
            for (int j = 0; j < 4; j++) a[j] = *(const float2*)&Xs[r0 + j][k];
            #pragma unroll
            for (int i = 0; i < 4; i++) b[i] = *(const float2*)&Ws[c0 + i][k];
            #pragma unroll
            for (int j = 0; j < 4; j++)
                #pragma unroll
                for (int i = 0; i < 4; i++)
                    acc[j][i] += a[j].x * b[i].x + a[j].y * b[i].y;
        }
    }
    float4 bi = *(const float4*)&bias[cb + c0];
    float scol[4] = {0.f, 0.f, 0.f, 0.f}, qcol[4] = {0.f, 0.f, 0.f, 0.f};
    #pragma unroll
    for (int j = 0; j < 4; j++) {
        float4 o;
        o.x = acc[j][0] + bi.x; o.y = acc[j][1] + bi.y;
        o.z = acc[j][2] + bi.z; o.w = acc[j][3] + bi.w;
        *(float4*)&Y[(size_t)(row0 + r0 + j) * Cout + cb + c0] = o;
        scol[0] += o.x; scol[1] += o.y; scol[2] += o.z; scol[3] += o.w;
        qcol[0] += o.x * o.x; qcol[1] += o.y * o.y;
        qcol[2] += o.z * o.z; qcol[3] += o.w * o.w;
    }
    if (outsum) {
        __syncthreads();
        #pragma unroll
        for (int i = 0; i < 4; i++) { Xs[ty][c0 + i] = scol[i]; Ws[ty][c0 + i] = qcol[i]; }
        __syncthreads();
        if (t < 64) {
            float ss = 0.f, qq = 0.f;
            #pragma unroll
            for (int r = 0; r < 16; r++) { ss += Xs[r][t]; qq += Ws[r][t]; }
            atomicAdd(&outsum[cb + t], ss);
            atomicAdd(&outsq[cb + t], qq);
        }
    }
}

// ================= rw1 gemm with analytic flat stats (no flatpre) =================
__launch_bounds__(256)
__global__ void k_gemm_rw1(const float* __restrict__ y2, const float* __restrict__ etot,
                           const float* __restrict__ s2sum, const float* __restrict__ s2sq,
                           const float* __restrict__ g2e, const float* __restrict__ b2e,
                           const float* __restrict__ g3, const float* __restrict__ b3,
                           const float* __restrict__ W, const float* __restrict__ bias,
                           float* __restrict__ Y,
                           float* __restrict__ osum, float* __restrict__ osq) {
    __shared__ float Xs[64][66];
    __shared__ float Ws[64][66];
    __shared__ float bsc[64], bsh[64];
    const int t = threadIdx.x;
    const int row0 = blockIdx.x * 64, cb = blockIdx.y * 64;
    const int tx = t & 15, ty = t >> 4;
    const int c0 = tx * 4, r0 = ty * 4;
    const int bb = row0 >> 12;
    if (t < 64) {
        const float iG = 1.0f / 4096.f, iNG = 1.0f / 16384.f;
        float S1 = s2sum[t], S2 = s2sq[t];
        float m2 = S1 * iG;
        float is2 = rsqrtf(S2 * iG - m2 * m2 + BNEPS);
        float sc2 = is2 * g2e[t], sh2 = b2e[t] - m2 * sc2;
        float sz = sc2 * S1 + 4096.f * sh2;
        float szz = sc2 * sc2 * S2 + 2.f * sc2 * sh2 * S1 + 4096.f * sh2 * sh2;
        float e0 = etot[t], e1 = etot[64 + t], e2 = etot[128 + t], e3 = etot[192 + t];
        float se = e0 + e1 + e2 + e3;
        float see = e0 * e0 + e1 * e1 + e2 * e2 + e3 * e3;
        float sumF = 4.f * sz + 4096.f * se;
        float sqF = 4.f * szz + 2.f * sz * se + 4096.f * see;
        float m3 = sumF * iNG;
        float is3 = rsqrtf(sqF * iNG - m3 * m3 + BNEPS);
        float eb = etot[bb * 64 + t];
        bsc[t] = sc2 * is3 * g3[t];
        bsh[t] = (sh2 + eb - m3) * is3 * g3[t] + b3[t];
    }
    __syncthreads();
    for (int i = t; i < 1024; i += 256) {
        int r = i >> 4, kq = (i & 15) * 4;
        int g = (row0 + r) & 4095;
        float4 v = *(const float4*)&y2[(size_t)g * 64 + kq];
        Xs[r][kq] = fmaxf(v.x * bsc[kq] + bsh[kq], 0.f);
        Xs[r][kq + 1] = fmaxf(v.y * bsc[kq + 1] + bsh[kq + 1], 0.f);
        Xs[r][kq + 2] = fmaxf(v.z * bsc[kq + 2] + bsh[kq + 2], 0.f);
        Xs[r][kq + 3] = fmaxf(v.w * bsc[kq + 3] + bsh[kq + 3], 0.f);
        float4 wv = *(const float4*)&W[(size_t)(cb + r) * 64 + kq];
        Ws[r][kq] = wv.x; Ws[r][kq + 1] = wv.y; Ws[r][kq + 2] = wv.z; Ws[r][kq + 3] = wv.w;
    }
    __syncthreads();
    float acc[4][4];
    #pragma unroll
    for (int j = 0; j < 4; j++)
        #pragma unroll
        for (int i = 0; i < 4; i++) acc[j][i] = 0.f;
    #pragma unroll 4
    for (int k = 0; k < 64; k += 2) {
        float2 a[4], b[4];
        #pragma unroll
        for (int j = 0; j < 4; j++) a[j] = *(const float2*)&Xs[r0 + j][k];
        #pragma unroll
        for (int i = 0; i < 4; i++) b[i] = *(const float2*)&Ws[c0 + i][k];
        #pragma unroll
        for (int j = 0; j < 4; j++)
            #pragma unroll
            for (int i = 0; i < 4; i++)
                acc[j][i] += a[j].x * b[i].x + a[j].y * b[i].y;
    }
    float4 bi = *(const float4*)&bias[cb + c0];
    float scol[4] = {0.f, 0.f, 0.f, 0.f}, qcol[4] = {0.f, 0.f, 0.f, 0.f};
    #pragma unroll
    for (int j = 0; j < 4; j++) {
        float4 o;
        o.x = acc[j][0] + bi.x; o.y = acc[j][1] + bi.y;
        o.z = acc[j][2] + bi.z; o.w = acc[j][3] + bi.w;
        *(float4*)&Y[(size_t)(row0 + r0 + j) * 128 + cb + c0] = o;
        scol[0] += o.x; scol[1] += o.y; scol[2] += o.z; scol[3] += o.w;
        qcol[0] += o.x * o.x; qcol[1] += o.y * o.y;
        qcol[2] += o.z * o.z; qcol[3] += o.w * o.w;
    }
    __syncthreads();
    #pragma unroll
    for (int i = 0; i < 4; i++) { Xs[ty][c0 + i] = scol[i]; Ws[ty][c0 + i] = qcol[i]; }
    __syncthreads();
    if (t < 64) {
        float ss = 0.f, qq = 0.f;
        #pragma unroll
        for (int r = 0; r < 16; r++) { ss += Xs[r][t]; qq += Ws[r][t]; }
        atomicAdd(&osum[cb + t], ss);
        atomicAdd(&osq[cb + t], qq);
    }
}

// ================= fused QKV gemm =================
__launch_bounds__(256)
__global__ void k_gemm_qkv(const float* __restrict__ X, const float* __restrict__ W,
                           const float* __restrict__ bias,
                           const float* __restrict__ bnsum, const float* __restrict__ bnsq,
                           const float* __restrict__ bng, const float* __restrict__ bnb,
                           ushort_t* __restrict__ Qb, ushort_t* __restrict__ Kb,
                           ushort_t* __restrict__ Vf) {
    __shared__ float Xs[64][66];
    __shared__ float Ws[64][66];
    __shared__ float bsc[64], bsh[64];
    const int t = threadIdx.x;
    const int row0 = blockIdx.x * 64, yb = blockIdx.y, cb = yb * 64;
    const int tx = t & 15, ty = t >> 4;
    const int c0 = tx * 4, r0 = ty * 4;
    const float invN = 1.0f / (float)(BB * GG);
    if (t < 64) {
        float m = bnsum[t] * invN;
        float is_ = rsqrtf(bnsq[t] * invN - m * m + BNEPS);
        float sc = is_ * bng[t];
        bsc[t] = sc; bsh[t] = bnb[t] - m * sc;
    }
    __syncthreads();
    for (int i = t; i < 1024; i += 256) {
        int r = i >> 4, kq = (i & 15) * 4;
        float4 v = *(const float4*)&X[(size_t)(row0 + r) * 64 + kq];
        Xs[r][kq] = v.x * bsc[kq] + bsh[kq];
        Xs[r][kq + 1] = v.y * bsc[kq + 1] + bsh[kq + 1];
        Xs[r][kq + 2] = v.z * bsc[kq + 2] + bsh[kq + 2];
        Xs[r][kq + 3] = v.w * bsc[kq + 3] + bsh[kq + 3];
        float4 wv = *(const float4*)&W[(size_t)(cb + r) * 64 + kq];
        Ws[r][kq] = wv.x; Ws[r][kq + 1] = wv.y; Ws[r][kq + 2] = wv.z; Ws[r][kq + 3] = wv.w;
    }
    __syncthreads();
    float acc[4][4];
    #pragma unroll
    for (int j = 0; j < 4; j++)
        #pragma unroll
        for (int i = 0; i < 4; i++) acc[j][i] = 0.f;
    #pragma unroll 4
    for (int k = 0; k < 64; k += 2) {
        float2 a[4], b[4];
        #pragma unroll
        for (int j = 0; j < 4; j++) a[j] = *(const float2*)&Xs[r0 + j][k];
        #pragma unroll
        for (int i = 0; i < 4; i++) b[i] = *(const float2*)&Ws[c0 + i][k];
        #pragma unroll
        for (int j = 0; j < 4; j++)
            #pragma unroll
            for (int i = 0; i < 4; i++)
                acc[j][i] += a[j].x * b[i].x + a[j].y * b[i].y;
    }
    float4 bi = *(const float4*)&bias[cb + c0];
    const int b2 = row0 >> 12, tile = (row0 & 4095) >> 6;
    if (yb < 2) {
        ushort_t* Dst = (yb == 0) ? Qb : Kb;
        const float sc2 = (yb == 0) ? QPRE : 1.0f;
        const int h = c0 >> 5, d = c0 & 31;
        #pragma unroll
        for (int j = 0; j < 4; j++) {
            union { ushort_t u[4]; uint2 v; } pk;
            pk.u[0] = f2b((acc[j][0] + bi.x) * sc2);
            pk.u[1] = f2b((acc[j][1] + bi.y) * sc2);
            pk.u[2] = f2b((acc[j][2] + bi.z) * sc2);
            pk.u[3] = f2b((acc[j][3] + bi.w) * sc2);
            int g = (row0 & 4095) + r0 + j;
            *(uint2*)&Dst[((size_t)(b2 * 2 + h) * GG + g) * 32 + d] = pk.v;
        }
    } else {
        __syncthreads();
        #pragma unroll
        for (int j = 0; j < 4; j++) {
            Xs[r0 + j][c0] = acc[j][0] + bi.x;
            Xs[r0 + j][c0 + 1] = acc[j][1] + bi.y;
            Xs[r0 + j][c0 + 2] = acc[j][2] + bi.z;
            Xs[r0 + j][c0 + 3] = acc[j][3] + bi.w;
        }
        __syncthreads();
        #pragma unroll
        for (int h = 0; h < 2; h++) {
            union { ushort_t u[8]; uint4 v; } pk;
            #pragma unroll
            for (int j = 0; j < 8; j++) {
                int idx = t * 8 + j;
                int g2 = idx >> 8, L = (idx >> 2) & 63, i = idx & 3;
                int key = (g2 >> 1) * 16 + ((L >> 4) << 2) + i;
                int d = ((g2 & 1) << 4) + (L & 15);
                pk.u[j] = f2b(Xs[key][h * 32 + d]);
            }
            *(uint4*)&Vf[((size_t)((b2 * 2 + h) * 64 + tile)) * 2048 + t * 8] = pk.v;
        }
    }
}

// ---- MFMA flash attention, 2-bh per block, 128-key tiles, 2-way split-k ----
// partials stored bf16; setprio around MFMA accumulate cluster (T5)
__launch_bounds__(512, 4)
__global__ void k_attn_mfma(const ushort_t* __restrict__ Qb, const ushort_t* __restrict__ Kb,
                            const ushort_t* __restrict__ Vf, const float* __restrict__ mask,
                            const float* __restrict__ mflag,
                            ushort_t* __restrict__ opA, ushort_t* __restrict__ opB,
                            float* __restrict__ Lp) {
    __shared__ ushort_t Kl[2][2][4096];   // 2buf x 2bh x (128 keys x 32 d)
    __shared__ ushort_t Vl[2][2][4096];
    const int split = blockIdx.y;
    const int bh0 = blockIdx.z * 2;
    const int q0 = blockIdx.x * 64;
    const int kstart = split * (GG / 2), kend = kstart + (GG / 2);
    const int t = threadIdx.x;
    const int lane = t & 63, w = t >> 6;
    const int qg = w >> 1, kh = w & 1;
    const int l15 = lane & 15, quad = lane >> 4;
    const int um = (*(const int*)mflag) != 0;   // wave-uniform

    sh8 qf[2];
    #pragma unroll
    for (int bh = 0; bh < 2; bh++)
        qf[bh] = *(const sh8*)&Qb[((size_t)(bh0 + bh) * GG + q0 + qg * 16 + l15) * 32 + quad * 8];
    const float* mrow = mask + (size_t)(q0 + qg * 16 + l15) * GG + quad * 4;

    auto stage = [&](int buf, int k0) {
        int bh = t >> 8, c = t & 255;     // 512 threads: 2bh x 256 chunks per 64-key half
        int key = ((c >> 6) << 4) + (c & 15);
        int chunk = (c >> 4) & 3;
        #pragma unroll
        for (int s = 0; s < 2; s++) {
            gld16(Kb + ((size_t)(bh0 + bh) * GG + k0 + s * 64 + key) * 32 + chunk * 8,
                  &Kl[buf][bh][s * 2048 + c * 8]);
            gld16(Vf + ((size_t)((bh0 + bh) * 64 + (k0 >> 6) + s)) * 2048 + c * 8,
                  &Vl[buf][bh][s * 2048 + c * 8]);
        }
    };
    stage(0, kstart);

    f4 O0[2], O1[2];
    float ls[2];
    #pragma unroll
    for (int bh = 0; bh < 2; bh++) {
        O0[bh] = f4{0.f, 0.f, 0.f, 0.f};
        O1[bh] = f4{0.f, 0.f, 0.f, 0.f};
        ls[bh] = 0.f;
    }

    auto run = [&](auto tag) {
        constexpr bool U = decltype(tag)::v;
        for (int k0 = kstart; k0 < kend; k0 += 128) {
            const int cur = ((k0 - kstart) >> 7) & 1;
            __syncthreads();
            if (k0 + 128 < kend) stage(cur ^ 1, k0 + 128);
            #pragma unroll
            for (int bh = 0; bh < 2; bh++) {
                #pragma unroll
                for (int ii = 0; ii < 4; ii++) {
                    const int i2 = kh * 4 + ii;
                    sh8 kf = *(const sh8*)&Kl[cur][bh][(i2 * 64 + lane) * 8];
                    f4 z = {0.f, 0.f, 0.f, 0.f};
                    __builtin_amdgcn_s_setprio(1);
                    f4 sa = __builtin_amdgcn_mfma_f32_16x16x32_bf16(kf, qf[bh], z, 0, 0, 0);
                    __builtin_amdgcn_s_setprio(0);
                    float p0, p1, p2, p3;
                    if constexpr (U) {
                        float4 mv = *(const float4*)&mrow[k0 + i2 * 16];
                        p0 = exp2f(fmaf(mv.x, LOG2E, sa[0]));
                        p1 = exp2f(fmaf(mv.y, LOG2E, sa[1]));
                        p2 = exp2f(fmaf(mv.z, LOG2E, sa[2]));
                        p3 = exp2f(fmaf(mv.w, LOG2E, sa[3]));
                    } else {
                        p0 = exp2f(sa[0]); p1 = exp2f(sa[1]);
                        p2 = exp2f(sa[2]); p3 = exp2f(sa[3]);
                    }
                    ls[bh] += (p0 + p1) + (p2 + p3);
                    // truncation pack f32->bf16 (round-toward-zero): P in (0,1],
                    // rel err <= 2^-8 on numerator only; well within threshold.
                    uint_t a0 = __builtin_bit_cast(uint_t, p0);
                    uint_t a1 = __builtin_bit_cast(uint_t, p1);
                    uint_t a2 = __builtin_bit_cast(uint_t, p2);
                    uint_t a3 = __builtin_bit_cast(uint_t, p3);
                    union { uint_t u[2]; sh4 v; } pkp;
                    pkp.u[0] = (a0 >> 16) | (a1 & 0xFFFF0000u);
                    pkp.u[1] = (a2 >> 16) | (a3 & 0xFFFF0000u);
                    sh4 vf0 = *(const sh4*)&Vl[cur][bh][((i2 * 2 + 0) * 64 + lane) * 4];
                    sh4 vf1 = *(const sh4*)&Vl[cur][bh][((i2 * 2 + 1) * 64 + lane) * 4];
                    __builtin_amdgcn_s_setprio(1);
                    O0[bh] = MFMA16(pkp.v, vf0, O0[bh]);
                    O1[bh] = MFMA16(pkp.v, vf1, O1[bh]);
                    __builtin_amdgcn_s_setprio(0);
                }
            }
        }
    };
    if (um) run(MaskOn{}); else run(MaskOff{});

    #pragma unroll
    for (int bh = 0; bh < 2; bh++) {
        ls[bh] += __shfl_xor(ls[bh], 16, 64);
        ls[bh] += __shfl_xor(ls[bh], 32, 64);
    }
    __syncthreads();
    float* Ox = (float*)&Kl[0][0][0];   // 2*64*32 floats = 16 KB (fits in Kl's 32 KB)
    float* Lx = (float*)&Vl[0][0][0];
    if (kh == 0) {
        #pragma unroll
        for (int bh = 0; bh < 2; bh++) {
            #pragma unroll
            for (int r = 0; r < 4; r++) {
                int ql = qg * 16 + quad * 4 + r;
                Ox[(bh * 64 + ql) * 32 + l15] = O0[bh][r];
                Ox[(bh * 64 + ql) * 32 + l15 + 16] = O1[bh][r];
            }
            if (quad == 0) Lx[bh * 64 + qg * 16 + l15] = ls[bh];
        }
    }
    __syncthreads();
    if (kh == 1) {
        ushort_t* op = (split == 0) ? opA : opB;
        #pragma unroll
        for (int bh = 0; bh < 2; bh++) {
            int gbh = bh0 + bh;
            #pragma unroll
            for (int r = 0; r < 4; r++) {
                int ql = qg * 16 + quad * 4 + r;
                size_t o = ((size_t)gbh * GG + q0 + ql) * 32 + l15;
                op[o] = f2b(O0[bh][r] + Ox[(bh * 64 + ql) * 32 + l15]);
                op[o + 16] = f2b(O1[bh][r] + Ox[(bh * 64 + ql) * 32 + l15 + 16]);
            }
            if (quad == 0)
                Lp[split * 32768 + gbh * GG + q0 + qg * 16 + l15] =
                    ls[bh] + Lx[bh * 64 + qg * 16 + l15];
        }
    }
}

// ===== k_comb: split-k combine + attn-out gemm + LN1 -> h1 bf16 (1024 blocks x 16 rows) =====
__launch_bounds__(256)
__global__ void k_comb(const ushort_t* __restrict__ opA, const ushort_t* __restrict__ opB,
                       const float* __restrict__ Lp, const float* __restrict__ yrw2,
                       const float* __restrict__ Waout, const float* __restrict__ baout,
                       const float* __restrict__ bsum5, const float* __restrict__ bsq5,
                       const float* __restrict__ bg5, const float* __restrict__ bb5,
                       const float* __restrict__ lg1, const float* __restrict__ lb1,
                       ushort_t* __restrict__ h1out) {
    __shared__ float Wt[4160];     // aout_w^T [64][65]
    __shared__ float Cs[1040];     // ctx [16][65]
    const int t = threadIdx.x;
    const int r0b = blockIdx.x * 16;
    const int lane = t & 63, w = t >> 6;
    for (int i = t; i < 4096; i += 256) Wt[(i & 63) * 65 + (i >> 6)] = Waout[i];
    {
        int col = t & 63, rl = t >> 6;
        int hh = col >> 5, d = col & 31;
        #pragma unroll
        for (int jj = 0; jj < 4; jj++) {
            int lrow = rl * 4 + jj;
            int row = r0b + lrow;
            int b = row >> 12, q = row & 4095;
            int bhq = (b * 2 + hh) * GG + q;
            size_t oi = (size_t)bhq * 32 + d;
            float num = b2f32(opA[oi]) + b2f32(opB[oi]);
            float den = Lp[bhq] + Lp[32768 + bhq];
            Cs[lrow * 65 + col] = num / den;
        }
    }
    __syncthreads();
    const float invN = 1.0f / (float)(BB * GG);
    float m5 = bsum5[lane] * invN;
    float is5 = rsqrtf(bsq5[lane] * invN - m5 * m5 + BNEPS);
    #pragma unroll
    for (int j = 0; j < 4; j++) {
        int lrow = w * 4 + j;
        int row = r0b + lrow;
        float acc = baout[lane];
        const float* cr = Cs + lrow * 65;
        #pragma unroll 8
        for (int k = 0; k < 64; k++) acc += cr[k] * Wt[k * 65 + lane];
        float ov = (yrw2[(size_t)row * 64 + lane] - m5) * is5 * bg5[lane] + bb5[lane];
        float v = ov + acc;
        float s = v;
        for (int o = 32; o > 0; o >>= 1) s += __shfl_xor(s, o, 64);
        float mean = s * (1.f / 64.f);
        float d = v - mean;
        float sq = d * d;
        for (int o = 32; o > 0; o >>= 1) sq += __shfl_xor(sq, o, 64);
        float inv = rsqrtf(sq * (1.f / 64.f) + BNEPS);
        h1out[(size_t)row * 64 + lane] = f2b(d * inv * lg1[lane] + lb1[lane]);
    }
}

// ===== k_ffn: FFN1 + FFN2 + LN2 + heads (256 blocks x 64 rows), h1 bf16 from global =====
__launch_bounds__(256)
__global__ void k_ffn(const ushort_t* __restrict__ h1b,
                      const ushort_t* __restrict__ W1b, const float* __restrict__ b1f,
                      const ushort_t* __restrict__ W2b, const float* __restrict__ b2f,
                      const float* __restrict__ lg2, const float* __restrict__ lb2,
                      const float* __restrict__ indvw, const float* __restrict__ indvb,
                      const float* __restrict__ hdc, const float* __restrict__ d2w,
                      const float* __restrict__ d2b, const float* __restrict__ x,
                      float* __restrict__ outp) {
    __shared__ ushort_t Hb[4096];   // h1 bf16 frags
    __shared__ ushort_t FT[32768];  // fft tile [w][16][64][8]
    __shared__ ushort_t WS[2][4096];
    const int t = threadIdx.x;
    const int r0b = blockIdx.x * 64;
    const int lane = t & 63, w = t >> 6;
    const int l15 = lane & 15, quad = lane >> 4;

    // copy h1 bf16 frags from global (already bf16 -> pure copy)
    if (t < 128) {
        int kt = t >> 6, lane6 = t & 63;
        int q2 = (lane6 >> 4) & 3, r15 = lane6 & 15;
        for (int rg = 0; rg < 4; rg++) {
            uint4 v4 = *(const uint4*)&h1b[(size_t)(r0b + rg * 16 + r15) * 64 + kt * 32 + q2 * 8];
            *(uint4*)&Hb[(rg * 2 + kt) * 512 + lane6 * 8] = v4;
        }
    }
    // FFN1: 8 colblocks, double-buffered weight staging
    auto stage1 = [&](int buf, int cb8) {
        int cb = cb8 * 64;
        #pragma unroll
        for (int kt = 0; kt < 2; kt++)
            gld16(W1b + (size_t)((cb + w * 16 + l15) * 64 + kt * 32 + quad * 8),
                  &WS[buf][(w * 2 + kt) * 512 + lane * 8]);
    };
    stage1(0, 0);
    for (int cb8 = 0; cb8 < 8; cb8++) {
        const int cur = cb8 & 1;
        __syncthreads();           // WS[cur] DMA done (+ Hb writes on first iter)
        if (cb8 + 1 < 8) stage1(cur ^ 1, cb8 + 1);
        sh8 xf0 = *(const sh8*)&Hb[(w * 2 + 0) * 512 + lane * 8];
        sh8 xf1 = *(const sh8*)&Hb[(w * 2 + 1) * 512 + lane * 8];
        const int cb = cb8 * 64;
        #pragma unroll
        for (int c = 0; c < 4; c++) {
            sh8 wf0 = *(const sh8*)&WS[cur][(c * 2 + 0) * 512 + lane * 8];
            sh8 wf1 = *(const sh8*)&WS[cur][(c * 2 + 1) * 512 + lane * 8];
            f4 z = {0.f, 0.f, 0.f, 0.f};
            __builtin_amdgcn_s_setprio(1);
            f4 acc = __builtin_amdgcn_mfma_f32_16x16x32_bf16(wf0, xf0, z, 0, 0, 0);
            acc = __builtin_amdgcn_mfma_f32_16x16x32_bf16(wf1, xf1, acc, 0, 0, 0);
            __builtin_amdgcn_s_setprio(0);
            float4 bv = *(const float4*)&b1f[cb + c * 16 + quad * 4];
            union { ushort_t u[4]; uint2 v2; } pk;
            pk.u[0] = f2b(fmaxf(acc[0] + bv.x, 0.f));
            pk.u[1] = f2b(fmaxf(acc[1] + bv.y, 0.f));
            pk.u[2] = f2b(fmaxf(acc[2] + bv.z, 0.f));
            pk.u[3] = f2b(fmaxf(acc[3] + bv.w, 0.f));
            int kt512 = cb8 * 2 + (c >> 1);
            int quadp = (c & 1) * 2 + (quad >> 1);
            int j0 = (quad & 1) * 4;
            *(uint2*)&FT[((w * 16 + kt512) * 64 + quadp * 16 + l15) * 8 + j0] = pk.v2;
        }
    }
    // FFN2: K=512, double-buffered weight staging, x-frags from FT
    auto stage2 = [&](int buf, int k0) {
        #pragma unroll
        for (int kt = 0; kt < 2; kt++)
            gld16(W2b + (size_t)((w * 16 + l15) * 512 + k0 + kt * 32 + quad * 8),
                  &WS[buf][(w * 2 + kt) * 512 + lane * 8]);
    };
    stage2(0, 0);
    f4 acc2[4];
    #pragma unroll
    for (int c = 0; c < 4; c++) acc2[c] = f4{0.f, 0.f, 0.f, 0.f};
    for (int k0 = 0; k0 < 512; k0 += 64) {
        const int cur = (k0 >> 6) & 1;
        __syncthreads();           // WS[cur] DMA done + (first iter) FT writes visible
        if (k0 + 64 < 512) stage2(cur ^ 1, k0 + 64);
        const int ktb = k0 >> 5;
        #pragma unroll
        for (int kt = 0; kt < 2; kt++) {
            sh8 xf = *(const sh8*)&FT[((w * 16 + ktb + kt) * 64 + lane) * 8];
            __builtin_amdgcn_s_setprio(1);
            #pragma unroll
            for (int c = 0; c < 4; c++) {
                sh8 wf = *(const sh8*)&WS[cur][(c * 2 + kt) * 512 + lane * 8];
                acc2[c] = __builtin_amdgcn_mfma_f32_16x16x32_bf16(wf, xf, acc2[c], 0, 0, 0);
            }
            __builtin_amdgcn_s_setprio(0);
        }
    }
    // epilogue: LN2 + per-gene head + recon
    const int row = r0b + w * 16 + l15;
    const int b = row >> 12, g = row & 4095;
    float v[4][4];
    float s = 0.f, sq = 0.f;
    #pragma unroll
    for (int c = 0; c < 4; c++) {
        float4 bv = *(const float4*)&b2f[c * 16 + quad * 4];
        uint2 hraw = *(const uint2*)&h1b[(size_t)row * 64 + c * 16 + quad * 4];
        ushort_t hu[4];
        hu[0] = (ushort_t)(hraw.x & 0xFFFFu); hu[1] = (ushort_t)(hraw.x >> 16);
        hu[2] = (ushort_t)(hraw.y & 0xFFFFu); hu[3] = (ushort_t)(hraw.y >> 16);
        #pragma unroll
        for (int i = 0; i < 4; i++) {
            float hv = b2f32(hu[i]);
            float bvi = (i == 0) ? bv.x : (i == 1) ? bv.y : (i == 2) ? bv.z : bv.w;
            v[c][i] = hv + acc2[c][i] + bvi;
            s += v[c][i]; sq += v[c][i] * v[c][i];
        }
    }
    s += __shfl_xor(s, 16, 64);  s += __shfl_xor(s, 32, 64);
    sq += __shfl_xor(sq, 16, 64); sq += __shfl_xor(sq, 32, 64);
    float mean = s * (1.f / 64.f);
    float inv = rsqrtf(sq * (1.f / 64.f) - mean * mean + BNEPS);
    float pd = 0.f;
    #pragma unroll
    for (int c = 0; c < 4; c++) {
        float4 lgv = *(const float4*)&lg2[c * 16 + quad * 4];
        float4 lbv = *(const float4*)&lb2[c * 16 + quad * 4];
        float4 iwv = *(const float4*)&indvw[(size_t)g * 64 + c * 16 + quad * 4];
        pd += ((v[c][0] - mean) * inv * lgv.x + lbv.x) * iwv.x;
        pd += ((v[c][1] - mean) * inv * lgv.y + lbv.y) * iwv.y;
        pd += ((v[c][2] - mean) * inv * lgv.z + lbv.z) * iwv.z;
        pd += ((v[c][3] - mean) * inv * lgv.w + lbv.w) * iwv.w;
    }
    float rc = 0.f;
    #pragma unroll
    for (int i = 0; i < 8; i++)
        rc += hdc[b * 32 + quad * 8 + i] * d2w[(size_t)g * 32 + quad * 8 + i];
    pd += __shfl_xor(pd, 16, 64); pd += __shfl_xor(pd, 32, 64);
    rc += __shfl_xor(rc, 16, 64); rc += __shfl_xor(rc, 32, 64);
    if (quad == 0) {
        float recon = rc + d2b[g];
        if (x[row] == 0.f) recon = 0.f;
        outp[row] = pd + indvb[g] + recon;
    }
}

extern "C" void kernel_launch(void* const* d_in, const int* in_sizes, int n_in,
                              void* d_out, int out_size, void* d_ws, size_t ws_size,
                              hipStream_t stream) {
    const float* x        = (const float*)d_in[0];
    const int*   pert_idx = (const int*)  d_in[1];
    const float* mask     = (const float*)d_in[2];
    const int*   ei_co    = (const int*)  d_in[3];
    const float* w_co     = (const float*)d_in[4];
    const int*   ei_go    = (const int*)  d_in[5];
    const float* w_go     = (const float*)d_in[6];
    const float* gene_emb = (const float*)d_in[7];
    const float* emb_pos  = (const float*)d_in[8];
    const float* pert_tbl = (const float*)d_in[9];
    const float* sg_co_w  = (const float*)d_in[10];
    const float* sg_co_b  = (const float*)d_in[11];
    const float* sg_go_w  = (const float*)d_in[12];
    const float* sg_go_b  = (const float*)d_in[13];
    const float* bn_emb_g = (const float*)d_in[14];
    const float* bn_emb_b = (const float*)d_in[15];
    const float* etv1_w   = (const float*)d_in[16];
    const float* etv1_b   = (const float*)d_in[17];
    const float* etv1_g   = (const float*)d_in[18];
    const float* etv1_be  = (const float*)d_in[19];
    const float* etv2_w   = (const float*)d_in[20];
    const float* etv2_b   = (const float*)d_in[21];
    const float* etv2_g   = (const float*)d_in[22];
    const float* etv2_be  = (const float*)d_in[23];
    const float* pf1_w    = (const float*)d_in[24];
    const float* pf1_b    = (const float*)d_in[25];
    const float* pf1_g    = (const float*)d_in[26];
    const float* pf1_be   = (const float*)d_in[27];
    const float* pf2_w    = (const float*)d_in[28];
    const float* pf2_b    = (const float*)d_in[29];
    const float* pf2_g    = (const float*)d_in[30];
    const float* pf2_be   = (const float*)d_in[31];
    const float* rw1_w    = (const float*)d_in[32];
    const float* rw1_b    = (const float*)d_in[33];
    const float* rw1_g    = (const float*)d_in[34];
    const float* rw1_be   = (const float*)d_in[35];
    const float* rw2_w    = (const float*)d_in[36];
    const float* rw2_b    = (const float*)d_in[37];
    const float* rw2_g    = (const float*)d_in[38];
    const float* rw2_be   = (const float*)d_in[39];
    const float* bnpb_g   = (const float*)d_in[40];
    const float* bnpb_b   = (const float*)d_in[41];
    const float* ain_w    = (const float*)d_in[42];
    const float* ain_b    = (const float*)d_in[43];
    const float* aout_w   = (const float*)d_in[44];
    const float* aout_b   = (const float*)d_in[45];
    const float* ln1_g    = (const float*)d_in[46];
    const float* ln1_b    = (const float*)d_in[47];
    const float* ff1_w    = (const float*)d_in[48];
    const float* ff1_b    = (const float*)d_in[49];
    const float* ff2_w    = (const float*)d_in[50];
    const float* ff2_b    = (const float*)d_in[51];
    const float* ln2_g    = (const float*)d_in[52];
    const float* ln2_b    = (const float*)d_in[53];
    const float* indv_w   = (const float*)d_in[54];
    const float* indv_b   = (const float*)d_in[55];
    const float* ve1_w    = (const float*)d_in[56];
    const float* ve1_b    = (const float*)d_in[57];
    const float* vmu_w    = (const float*)d_in[58];
    const float* vmu_b    = (const float*)d_in[59];
    const float* vlv_w    = (const float*)d_in[60];
    const float* vlv_b    = (const float*)d_in[61];
    const float* vd1_w    = (const float*)d_in[62];
    const float* vd1_b    = (const float*)d_in[63];
    const float* vd2_w    = (const float*)d_in[64];
    const float* vd2_b    = (const float*)d_in[65];
    const float* veps     = (const float*)d_in[66];

    float* ws   = (float*)d_ws;
    float* outp = (float*)d_out;

    float* stm1 = ws + OF_STATS + 1 * 256; float* sti1 = stm1 + 128;
    float* stm2 = ws + OF_STATS + 2 * 256; float* sti2 = stm2 + 128;
    float* stm4 = ws + OF_STATS + 4 * 256; float* sti4 = stm4 + 128;
    float* stm5 = ws + OF_STATS + 5 * 256; float* sti5 = stm5 + 128;

    float* basein = ws + OF_BASEIN;
    float* y1     = ws + OF_Y1;
    float* y2     = ws + OF_Y2;
    float* yrw1   = ws + OF_RW1;
    float* yrw2   = ws + OF_RW2;
    ushort_t* opA = (ushort_t*)(ws + OF_OPA);
    ushort_t* opB = (ushort_t*)(ws + OF_OPB);
    float* Lp     = ws + OF_LP;
    ushort_t* h1buf = (ushort_t*)(ws + OF_H1);
    ushort_t* Qb  = (ushort_t*)(ws + OF_QB);
    ushort_t* Kb  = (ushort_t*)(ws + OF_KB);
    ushort_t* Vf  = (ushort_t*)(ws + OF_VF);
    ushort_t* W1b = (ushort_t*)(ws + OF_W1B);
    ushort_t* W2b = (ushort_t*)(ws + OF_W2B);

    const int NG = BB * GG; // 16384
    const float iG = 1.0f / (float)GG, iNG = 1.0f / (float)NG;

    // zero stats+deg+pslot+etot/hdc/he+mflag (contiguous) and edge-count histogram
    hipMemsetAsync(ws, 0, 11268 * sizeof(float), stream);
    hipMemsetAsync(ws + OF_CNT, 0, 4096 * sizeof(int), stream);

    // K12: degrees + co edge counts, gene_emb stats, vae_he, FFN weight->bf16, mask scan
    k_fat12<<<1792, 256, 0, stream>>>(ws, ei_co, w_co, ei_go, w_go, gene_emb,
                                      x, ve1_w, ve1_b, ff1_w, ff2_w, mask);
    // CSR offsets for co edges
    k_scan<<<1, 256, 0, stream>>>(ws);
    // K3: edge scatter (CSR sort) + pert edge scan + vae_mid
    k_fat3<<<641, 256, 0, stream>>>(ws, ei_co, w_co, pert_idx,
                                    ei_go, w_go, pert_tbl,
                                    vmu_w, vmu_b, vlv_w, vlv_b, vd1_w, vd1_b,
                                    veps, outp + NG);
    // K4: base_combine (fused CSR gather) + pert MLP
    k_fat4<<<1025, 256, 0, stream>>>(ws, gene_emb, emb_pos, sg_co_w, sg_co_b,
                                     bn_emb_g, bn_emb_b, pert_idx, pert_tbl,
                                     sg_go_w, sg_go_b,
                                     pf1_w, pf1_b, pf1_g, pf1_be,
                                     pf2_w, pf2_b, pf2_g, pf2_be);
    // etv MLP
    k_gemm64<<<dim3(GG / 64, 1), 256, 0, stream>>>(basein, etv1_w, etv1_b, y1, 64, 64,
                                                   nullptr, nullptr, nullptr, nullptr, 0.f, 0,
                                                   stm1, sti1);
    k_gemm64<<<dim3(GG / 64, 1), 256, 0, stream>>>(y1, etv2_w, etv2_b, y2, 64, 64,
                                                   stm1, sti1, etv1_g, etv1_be, iG, 1,
                                                   stm2, sti2);
    // rw MLP (analytic flat stats; no flatpre)
    k_gemm_rw1<<<dim3(NG / 64, 2), 256, 0, stream>>>(y2, ws + OF_ETOT, stm2, sti2,
                                                     etv2_g, etv2_be, bnpb_g, bnpb_b,
                                                     rw1_w, rw1_b, yrw1, stm4, sti4);
    k_gemm64<<<dim3(NG / 64, 1), 256, 0, stream>>>(yrw1, rw2_w, rw2_b, yrw2, 128, 64,
                                                   stm4, sti4, rw1_g, rw1_be, iNG, 1,
                                                   stm5, sti5);
    // transformer
    k_gemm_qkv<<<dim3(NG / 64, 3), 256, 0, stream>>>(yrw2, ain_w, ain_b,
                                                     stm5, sti5, rw2_g, rw2_be,
                                                     Qb, Kb, Vf);
    k_attn_mfma<<<dim3(GG / 64, 2, 4), 512, 0, stream>>>(Qb, Kb, Vf, mask,
                                                         ws + OF_MFLAG, opA, opB, Lp);
    // combine + attn-out + LN1 (wide grid, high occupancy) -> h1 bf16
    k_comb<<<NG / 16, 256, 0, stream>>>(opA, opB, Lp, yrw2, aout_w, aout_b,
                                        stm5, sti5, rw2_g, rw2_be, ln1_g, ln1_b, h1buf);
    // FFN + LN2 + heads
    k_ffn<<<NG / 64, 256, 0, stream>>>(h1buf, W1b, ff1_b, W2b, ff2_b, ln2_g, ln2_b,
                                       indv_w, indv_b, ws + OF_HDC, vd2_w, vd2_b,
                                       x, outp);
}

// Round 14
// 431.444 us; speedup vs baseline: 1.0340x; 1.0340x over previous
//
#include <hip/hip_runtime.h>
#include <hip/hip_bf16.h>
#include <math.h>

#define GG 4096
#define PP 4096
#define HH 64
#define BB 4
#define E1N 81920
#define E2N 81920
#define FFD 512
#define BNEPS 1e-5f
#define LOG2E 1.44269504088896341f
#define QPRE (0.17677669529663687f * LOG2E)

typedef unsigned short ushort_t;
typedef unsigned int uint_t;
using sh8 = __attribute__((ext_vector_type(8))) short;
using sh4 = __attribute__((ext_vector_type(4))) short;
using f4  = __attribute__((ext_vector_type(4))) float;

struct MaskOn  { static constexpr bool v = true; };
struct MaskOff { static constexpr bool v = false; };

#if __has_builtin(__builtin_amdgcn_mfma_f32_16x16x16bf16_1k)
#define MFMA16(a, b, c) __builtin_amdgcn_mfma_f32_16x16x16bf16_1k((a), (b), (c), 0, 0, 0)
#elif __has_builtin(__builtin_amdgcn_mfma_f32_16x16x16_bf16)
#define MFMA16(a, b, c) __builtin_amdgcn_mfma_f32_16x16x16_bf16((a), (b), (c), 0, 0, 0)
#else
static __device__ inline f4 mfma16_asm(sh4 a, sh4 b, f4 c) {
    f4 d;
    asm volatile("v_mfma_f32_16x16x16_bf16 %0, %1, %2, %3"
                 : "=v"(d) : "v"(a), "v"(b), "v"(c));
    return d;
}
#define MFMA16(a, b, c) mfma16_asm((a), (b), (c))
#endif

// ---------------- workspace layout (float offsets) ----------------
#define OF_STATS   0          // 6 slots x 256 (raw sum[128] + sumsq[128])
#define OF_DEGCO   2048
#define OF_DEGGO   6144
#define OF_PSLOT   10240
#define OF_ETOT    10752
#define OF_HDC     11008
#define OF_HE      11136
#define OF_MFLAG   11264      // int: 1 if mask has any nonzero bits
// CSR sort of co-expression edges (lives in dead AGGCO region 12288..274432)
#define OF_CNT     12288      // int[4096]  edge counts per dst
#define OF_OFFS    16384      // int[4097]  CSR offsets
#define OF_WOFF    20608      // int[4096]  scatter cursors
#define OF_SSRC    24704      // int[81920] sorted src
#define OF_SNRM    106624     // f32[81920] sorted norm
#define OF_BASEIN  274432
#define OF_Y1      536576
#define OF_Y2      798720
#define OF_FLAT    1060864    // (Vf region)
#define OF_RW1     2109440    // 16384 x 128
#define OF_RW2     4206592    // 16384 x 64
#define OF_OUT     5255168    // attn split 1 partial (bf16)
#define OF_QKV     6303744    // attn split 0 partial (bf16)
// bf16 attention buffers (alias dead fp32 regions)
#define OF_QB      12288      // 8*4096*32 ushort (dead CSR region by QKV time)
#define OF_KB      (OF_QB + 524288)
#define OF_VF      OF_FLAT    // 8*64*2048 ushort (V frag-order)
// attention k-split partials
#define OF_OPA     OF_QKV
#define OF_OPB     OF_OUT
#define OF_LP      OF_RW1     // 2*8*4096
#define OF_H1      (OF_RW1 + 131072)   // bf16[16384*64] post-LN1 h1 (dead yrw1 region)
#define OPS        1048576
// FFN bf16 weights (dead FFO region)
#define OF_W1B     9449472    // 512*64 bf16
#define OF_W2B     9465856    // 64*512 bf16

__device__ inline ushort_t f2b(float f) {
    uint_t u = __builtin_bit_cast(uint_t, f);
    u += 0x7FFFu + ((u >> 16) & 1u);
    return (ushort_t)(u >> 16);
}

__device__ inline float b2f32(ushort_t u) {
    return __builtin_bit_cast(float, (uint_t)u << 16);
}

__device__ inline void gld16(const void* gptr, void* lptr) {
    __builtin_amdgcn_global_load_lds(
        (const __attribute__((address_space(1))) uint_t*)gptr,
        (__attribute__((address_space(3))) uint_t*)lptr, 16, 0, 0);
}

// ================= device sub-kernels =================
__device__ void dev_vae_he(int bid, const float* __restrict__ x, const float* __restrict__ W,
                           const float* __restrict__ bias, float* he, float* sh) {
    int b = bid >> 5, i = bid & 31;
    float s = 0.f;
    for (int g = threadIdx.x; g < 4096; g += 256) s += x[b * 4096 + g] * W[i * 4096 + g];
    sh[threadIdx.x] = s;
    __syncthreads();
    for (int o = 128; o > 0; o >>= 1) {
        if (threadIdx.x < o) sh[threadIdx.x] += sh[threadIdx.x + o];
        __syncthreads();
    }
    if (threadIdx.x == 0) he[b * 32 + i] = fmaxf(sh[0] + bias[i], 0.f);
}

__device__ void dev_vae_mid(const float* __restrict__ he,
                            const float* __restrict__ muw, const float* __restrict__ mub,
                            const float* __restrict__ lvw, const float* __restrict__ lvb,
                            const float* __restrict__ d1w, const float* __restrict__ d1b,
                            const float* __restrict__ eps, float* hdc, float* klout, float* zs) {
    int t = threadIdx.x;
    if (t < 64) {
        int b = t >> 4, l = t & 15;
        float mu = mub[l], lv = lvb[l];
        for (int i = 0; i < 32; i++) {
            float hv = he[b * 32 + i];
            mu += hv * muw[l * 32 + i];
            lv += hv * lvw[l * 32 + i];
        }
        zs[t] = mu + eps[t] * expf(0.5f * lv);
        float kterm = 1.f + lv - mu * mu - expf(lv);
        for (int o = 32; o > 0; o >>= 1) kterm += __shfl_xor(kterm, o, 64);
        if (t == 0) klout[0] = -0.5f * kterm * 0.25f;
    }
    __syncthreads();
    if (t < 128) {
        int b = t >> 5, i = t & 31;
        float a = d1b[i];
        for (int l = 0; l < 16; l++) a += zs[b * 16 + l] * d1w[i * 16 + l];
        hdc[t] = fmaxf(a, 0.f);
    }
}

__device__ void dev_edge_deg(int bid, const int* __restrict__ ei, const float* __restrict__ w,
                             float* deg, int E, int* cnt) {
    int e = bid * 256 + threadIdx.x;
    if (e < E) {
        int d = ei[E + e];
        atomicAdd(&deg[d], w[e]);
        if (cnt) atomicAdd(&cnt[d], 1);
    }
}

__device__ void dev_cs_part(int bid, const float* __restrict__ X, int N,
                            float* sum, float* sumsq, float* sh) {
    int t = threadIdx.x;
    int col = t & 63, ro = t >> 6;
    int rows = N >> 8;
    int r0 = bid * rows;
    float s = 0.f, q = 0.f;
    for (int r = r0 + ro; r < r0 + rows; r += 4) {
        float v = X[r * 64 + col];
        s += v; q += v * v;
    }
    float* ls = sh; float* lq = sh + 256;
    ls[t] = s; lq[t] = q;
    __syncthreads();
    if (t < 64) {
        for (int j = t + 64; j < 256; j += 64) { s += ls[j]; q += lq[j]; }
        atomicAdd(&sum[t], s);
        atomicAdd(&sumsq[t], q);
    }
}

// bitwise OR-scan of mask; sets flag if any nonzero bits (conservative: -0.0 counts)
__device__ void dev_mask_scan(int bid, const float* __restrict__ mask, int* flag) {
    const uint4* m4 = (const uint4*)mask;
    const int total = (GG * GG) / 4;          // 4,194,304 uint4
    uint_t acc = 0u;
    for (int i = bid * 256 + threadIdx.x; i < total; i += 512 * 256) {
        uint4 v = m4[i];
        acc |= v.x | v.y | v.z | v.w;
    }
    if (acc) atomicOr(flag, 1);
}

// scatter co-edges into CSR order (pos via cursor atomic; 4B traffic only)
__device__ void dev_scatter(int bid, const int* __restrict__ ei, const float* __restrict__ w,
                            const float* __restrict__ deg,
                            int* woff, int* ssrc, float* snrm) {
    int e = bid * 256 + threadIdx.x;
    if (e >= E1N) return;
    int src = ei[e], dst = ei[E1N + e];
    float nrm = rsqrtf(deg[dst] + 1.f) * w[e] * rsqrtf(deg[src] + 1.f);
    int pos = atomicAdd(&woff[dst], 1);
    ssrc[pos] = src;
    snrm[pos] = nrm;
}

// wave-cooperative pert-edge accumulation (matches are rare: ballot + broadcast)
__device__ void dev_pert_edges(int bid, const int* __restrict__ pidx, const int* __restrict__ ei,
                               const float* __restrict__ w, const float* __restrict__ deg,
                               const float* __restrict__ tbl, float* pslot) {
    int e = bid * 256 + threadIdx.x;
    int lane = threadIdx.x & 63;
    bool valid = e < E2N;
    int dst = valid ? ei[E2N + e] : -1;
    int hit = 0;
    #pragma unroll
    for (int s = 0; s < 8; s++) hit |= (pidx[s] == dst) ? (1 << s) : 0;
    if (__ballot(hit != 0) == 0) return;          // whole-wave fast exit
    int src = valid ? ei[e] : 0;
    float nrm = 0.f;
    if (hit) nrm = rsqrtf(deg[dst] + 1.f) * w[e] * rsqrtf(deg[src] + 1.f);
    for (int s = 0; s < 8; s++) {
        unsigned long long m = __ballot((hit >> s) & 1);
        while (m) {
            int l = __builtin_ctzll(m);
            m &= m - 1;
            int es = __shfl(src, l, 64);
            float en = __shfl(nrm, l, 64);
            atomicAdd(&pslot[s * 64 + lane], en * tbl[es * 64 + lane]);
        }
    }
}

// base combine with fused CSR gather (no agg buffer, no atomics)
__device__ void dev_base_combine(int bid, const float* __restrict__ gene_emb,
                                 const int* __restrict__ off, const int* __restrict__ ssrc,
                                 const float* __restrict__ snrm,
                                 const float* __restrict__ emb_pos,
                                 const float* __restrict__ deg,
                                 const float* __restrict__ W, const float* __restrict__ bias,
                                 const float* __restrict__ bsum, const float* __restrict__ bsq,
                                 const float* __restrict__ bg, const float* __restrict__ bb,
                                 float* out, float* sh) {
    float* Wt = sh;            // [64][65]
    float* a = sh + 4160;      // [4][64]
    int t = threadIdx.x;
    for (int i = t; i < 4096; i += 256) Wt[(i & 63) * 65 + (i >> 6)] = W[i];
    int rr = t >> 6, h = t & 63;
    int g = bid * 4 + rr;
    float acc = emb_pos[g * 64 + h] / (deg[g] + 1.f);   // self-loop term
    int e = off[g];
    const int e1 = off[g + 1];
    for (; e + 4 <= e1; e += 4) {
        int s0 = ssrc[e], s1 = ssrc[e + 1], s2 = ssrc[e + 2], s3 = ssrc[e + 3];
        float n0 = snrm[e], n1 = snrm[e + 1], n2 = snrm[e + 2], n3 = snrm[e + 3];
        acc += n0 * emb_pos[s0 * 64 + h];
        acc += n1 * emb_pos[s1 * 64 + h];
        acc += n2 * emb_pos[s2 * 64 + h];
        acc += n3 * emb_pos[s3 * 64 + h];
    }
    for (; e < e1; e++) acc += snrm[e] * emb_pos[ssrc[e] * 64 + h];
    a[rr * 64 + h] = acc;
    __syncthreads();
    float y = bias[h];
    const float* ar = a + rr * 64;
    #pragma unroll 8
    for (int k = 0; k < 64; k++) y += ar[k] * Wt[k * 65 + h];
    const float invN = 1.0f / (float)GG;
    float m = bsum[h] * invN;
    float is_ = rsqrtf(bsq[h] * invN - m * m + BNEPS);
    float v = gene_emb[g * 64 + h];
    v = (v - m) * is_ * bg[h] + bb[h];
    v = fmaxf(v, 0.f);
    out[g * 64 + h] = v + 0.2f * y;
}

__device__ void dev_pert_mlp(const float* __restrict__ pslot, const int* __restrict__ pidx,
                             const float* __restrict__ deg, const float* __restrict__ tbl,
                             const float* __restrict__ gw, const float* __restrict__ gb,
                             const float* __restrict__ w1, const float* __restrict__ b1,
                             const float* __restrict__ g1, const float* __restrict__ be1,
                             const float* __restrict__ w2, const float* __restrict__ b2,
                             const float* __restrict__ g2, const float* __restrict__ be2,
                             float* etot, float* sh) {
    float* pge = sh;
    float* psum = sh + 512;
    float* y = sh + 768;
    float* mh = sh + 1024;
    float* ih = sh + 1088;
    int t = threadIdx.x;
    for (int j = t; j < 512; j += 256) {
        int s = j >> 6, h = j & 63;
        int n = pidx[s];
        float invd = 1.0f / (deg[n] + 1.f);
        float acc = gb[h];
        for (int k = 0; k < 64; k++)
            acc += (pslot[s * 64 + k] + tbl[n * 64 + k] * invd) * gw[h * 64 + k];
        pge[j] = acc;
    }
    __syncthreads();
    { int b = t >> 6, h = t & 63; psum[t] = pge[2 * b * 64 + h] + pge[(2 * b + 1) * 64 + h]; }
    __syncthreads();
    { int h = t & 63; int b = t >> 6;
      float acc = b1[h];
      for (int k = 0; k < 64; k++) acc += psum[b * 64 + k] * w1[h * 64 + k];
      y[t] = acc; }
    __syncthreads();
    if (t < 64) {
        float s = 0.f, sq = 0.f;
        for (int b = 0; b < 4; b++) { float v = y[b * 64 + t]; s += v; sq += v * v; }
        float m = s * 0.25f;
        mh[t] = m; ih[t] = rsqrtf(sq * 0.25f - m * m + BNEPS);
    }
    __syncthreads();
    { int h = t & 63;
      float v = (y[t] - mh[h]) * ih[h] * g1[h] + be1[h];
      psum[t] = fmaxf(v, 0.f); }
    __syncthreads();
    { int h = t & 63; int b = t >> 6;
      float acc = b2[h];
      for (int k = 0; k < 64; k++) acc += psum[b * 64 + k] * w2[h * 64 + k];
      y[t] = acc; }
    __syncthreads();
    if (t < 64) {
        float s = 0.f, sq = 0.f;
        for (int b = 0; b < 4; b++) { float v = y[b * 64 + t]; s += v; sq += v * v; }
        float m = s * 0.25f;
        mh[t] = m; ih[t] = rsqrtf(sq * 0.25f - m * m + BNEPS);
    }
    __syncthreads();
    { int h = t & 63;
      etot[t] = (y[t] - mh[h]) * ih[h] * g2[h] + be2[h]; }
}

// ================= fat kernels =================
// K12: edge_deg co+cnt(320) | edge_deg go(320) | cs_part gene_emb(256) | vae_he(128)
//      | W->bf16(256) | mask_scan(512)
__global__ void k_fat12(float* ws, const int* __restrict__ ei_co, const float* __restrict__ w_co,
                        const int* __restrict__ ei_go, const float* __restrict__ w_go,
                        const float* __restrict__ gene_emb, const float* __restrict__ x,
                        const float* __restrict__ ve1_w, const float* __restrict__ ve1_b,
                        const float* __restrict__ ff1_w, const float* __restrict__ ff2_w,
                        const float* __restrict__ mask) {
    __shared__ float sh[512];
    int bid = blockIdx.x;
    if (bid < 320) dev_edge_deg(bid, ei_co, w_co, ws + OF_DEGCO, E1N, (int*)(ws + OF_CNT));
    else if (bid < 640) dev_edge_deg(bid - 320, ei_go, w_go, ws + OF_DEGGO, E2N, nullptr);
    else if (bid < 896) dev_cs_part(bid - 640, gene_emb, GG, ws + OF_STATS, ws + OF_STATS + 128, sh);
    else if (bid < 1024) dev_vae_he(bid - 896, x, ve1_w, ve1_b, ws + OF_HE, sh);
    else if (bid < 1280) {
        int i = (bid - 1024) * 256 + threadIdx.x;   // 256 blocks -> 65536
        ushort_t* W1b = (ushort_t*)(ws + OF_W1B);
        ushort_t* W2b = (ushort_t*)(ws + OF_W2B);
        if (i < 32768) W1b[i] = f2b(ff1_w[i]);
        else W2b[i - 32768] = f2b(ff2_w[i - 32768]);
    } else dev_mask_scan(bid - 1280, mask, (int*)(ws + OF_MFLAG));
}

// KSCAN: exclusive prefix sum of cnt[4096] -> off[4097] (+ mutable cursor copy)
__global__ void k_scan(float* ws) {
    int* cnt = (int*)(ws + OF_CNT);
    int* off = (int*)(ws + OF_OFFS);
    int* woff = (int*)(ws + OF_WOFF);
    __shared__ int part[256];
    const int t = threadIdx.x;
    int loc[16];
    int s = 0;
    #pragma unroll
    for (int i = 0; i < 16; i++) { loc[i] = s; s += cnt[t * 16 + i]; }
    part[t] = s;
    __syncthreads();
    for (int o = 1; o < 256; o <<= 1) {
        int v = (t >= o) ? part[t - o] : 0;
        __syncthreads();
        part[t] += v;
        __syncthreads();
    }
    int prev = (t == 0) ? 0 : part[t - 1];
    #pragma unroll
    for (int i = 0; i < 16; i++) {
        int o = prev + loc[i];
        off[t * 16 + i] = o;
        woff[t * 16 + i] = o;
    }
    if (t == 255) off[4096] = part[255];
}

// K3: scatter(320) | pert_edges(320) | vae_mid(1)
__global__ void k_fat3(float* ws, const int* __restrict__ ei_co, const float* __restrict__ w_co,
                       const int* __restrict__ pidx,
                       const int* __restrict__ ei_go, const float* __restrict__ w_go,
                       const float* __restrict__ pert_tbl,
                       const float* __restrict__ vmu_w, const float* __restrict__ vmu_b,
                       const float* __restrict__ vlv_w, const float* __restrict__ vlv_b,
                       const float* __restrict__ vd1_w, const float* __restrict__ vd1_b,
                       const float* __restrict__ veps, float* klout) {
    __shared__ float sh[512];
    int bid = blockIdx.x;
    if (bid < 320)
        dev_scatter(bid, ei_co, w_co, ws + OF_DEGCO,
                    (int*)(ws + OF_WOFF), (int*)(ws + OF_SSRC), ws + OF_SNRM);
    else if (bid < 640)
        dev_pert_edges(bid - 320, pidx, ei_go, w_go, ws + OF_DEGGO, pert_tbl, ws + OF_PSLOT);
    else dev_vae_mid(ws + OF_HE, vmu_w, vmu_b, vlv_w, vlv_b, vd1_w, vd1_b, veps,
                     ws + OF_HDC, klout, sh);
}

// K4: base_combine+gather(1024) | pert_mlp(1)
__global__ void k_fat4(float* ws, const float* __restrict__ gene_emb,
                       const float* __restrict__ emb_pos,
                       const float* __restrict__ sg_co_w, const float* __restrict__ sg_co_b,
                       const float* __restrict__ bn_emb_g, const float* __restrict__ bn_emb_b,
                       const int* __restrict__ pidx, const float* __restrict__ pert_tbl,
                       const float* __restrict__ gw, const float* __restrict__ gb,
                       const float* __restrict__ w1, const float* __restrict__ b1,
                       const float* __restrict__ g1, const float* __restrict__ be1,
                       const float* __restrict__ w2, const float* __restrict__ b2,
                       const float* __restrict__ g2, const float* __restrict__ be2) {
    __shared__ float sh[4416];
    int bid = blockIdx.x;
    if (bid < 1024)
        dev_base_combine(bid, gene_emb, (const int*)(ws + OF_OFFS),
                         (const int*)(ws + OF_SSRC), ws + OF_SNRM,
                         emb_pos, ws + OF_DEGCO,
                         sg_co_w, sg_co_b, ws + OF_STATS, ws + OF_STATS + 128,
                         bn_emb_g, bn_emb_b, ws + OF_BASEIN, sh);
    else
        dev_pert_mlp(ws + OF_PSLOT, pidx, ws + OF_DEGGO, pert_tbl, gw, gb,
                     w1, b1, g1, be1, w2, b2, g2, be2, ws + OF_ETOT, sh);
}

// ================= gemm64 (fp32, etv/rw chain) =================
__launch_bounds__(256)
__global__ void k_gemm64(const float* __restrict__ X, const float* __restrict__ W,
                         const float* __restrict__ bias, float* __restrict__ Y,
                         int Cin, int Cout,
                         const float* __restrict__ bnsum, const float* __restrict__ bnsq,
                         const float* __restrict__ bng, const float* __restrict__ bnb,
                         float invN, int relu_in,
                         float* __restrict__ outsum, float* __restrict__ outsq) {
    __shared__ float Xs[64][66];
    __shared__ float Ws[64][66];
    __shared__ float bsc[64], bsh[64];
    const int t = threadIdx.x;
    const int row0 = blockIdx.x * 64, cb = blockIdx.y * 64;
    const int tx = t & 15, ty = t >> 4;
    const int c0 = tx * 4, r0 = ty * 4;
    float acc[4][4];
    #pragma unroll
    for (int j = 0; j < 4; j++)
        #pragma unroll
        for (int i = 0; i < 4; i++) acc[j][i] = 0.f;

    for (int k0 = 0; k0 < Cin; k0 += 64) {
        __syncthreads();
        if (t < 64) {
            float sc = 1.f, sh = 0.f;
            if (bnsum) {
                int c = k0 + t;
                float m = bnsum[c] * invN;
                float is_ = rsqrtf(bnsq[c] * invN - m * m + BNEPS);
                sc = is_ * bng[c]; sh = bnb[c] - m * sc;
            }
            bsc[t] = sc; bsh[t] = sh;
        }
        __syncthreads();
        for (int i = t; i < 1024; i += 256) {
            int r = i >> 4, kq = (i & 15) * 4;
            float4 v = *(const float4*)&X[(size_t)(row0 + r) * Cin + k0 + kq];
            float e0 = v.x * bsc[kq] + bsh[kq];
            float e1 = v.y * bsc[kq + 1] + bsh[kq + 1];
            float e2 = v.z * bsc[kq + 2] + bsh[kq + 2];
            float e3 = v.w * bsc[kq + 3] + bsh[kq + 3];
            if (relu_in) {
                e0 = fmaxf(e0, 0.f); e1 = fmaxf(e1, 0.f);
                e2 = fmaxf(e2, 0.f); e3 = fmaxf(e3, 0.f);
            }
            Xs[r][kq] = e0; Xs[r][kq + 1] = e1; Xs[r][kq + 2] = e2; Xs[r][kq + 3] = e3;
            float4 wv = *(const float4*)&W[(size_t)(cb + r) * Cin + k0 + kq];
            Ws[r][kq] = wv.x; Ws[r][kq + 1] = wv.y; Ws[r][kq + 2] = wv.z; Ws[r][kq + 3] = wv.w;
        }
        __syncthreads();
        #pragma unroll 4
        for (int k = 0; k < 64; k += 2) {
            float2 a[4], b[4];
            #pragma unroll
            for (int j = 0; j < 4; j++) a[j] = *(const float2*)&Xs[r0 + j][k];
            #pragma unroll
            for (int i = 0; i < 4; i++) b[i] = *(const float2*)&Ws[c0 + i][k];
            #pragma unroll
            for (int j = 0; j < 4; j++)
                #pragma unroll
                for (int i = 0; i < 4; i++)
                    acc[j][i] += a[j].x * b[i].x + a[j].y * b[i].y;
        }
    }
    float4 bi = *(const float4*)&bias[cb + c0];
    float scol[4] = {0.f, 0.f, 0.f, 0.f}, qcol[4] = {0.f, 0.f, 0.f, 0.f};
    #pragma unroll
    for (int j = 0; j < 4; j++) {
        float4 o;
        o.x = acc[j][0] + bi.x; o.y = acc[j][1] + bi.y;
        o.z = acc[j][2] + bi.z; o.w = acc[j][3] + bi.w;
        *(float4*)&Y[(size_t)(row0 + r0 + j) * Cout + cb + c0] = o;
        scol[0] += o.x; scol[1] += o.y; scol[2] += o.z; scol[3] += o.w;
        qcol[0] += o.x * o.x; qcol[1] += o.y * o.y;
        qcol[2] += o.z * o.z; qcol[3] += o.w * o.w;
    }
    if (outsum) {
        __syncthreads();
        #pragma unroll
        for (int i = 0; i < 4; i++) { Xs[ty][c0 + i] = scol[i]; Ws[ty][c0 + i] = qcol[i]; }
        __syncthreads();
        if (t < 64) {
            float ss = 0.f, qq = 0.f;
            #pragma unroll
            for (int r = 0; r < 16; r++) { ss += Xs[r][t]; qq += Ws[r][t]; }
            atomicAdd(&outsum[cb + t], ss);
            atomicAdd(&outsq[cb + t], qq);
        }
    }
}

// ================= rw1 gemm with analytic flat stats (no flatpre) =================
__launch_bounds__(256)
__global__ void k_gemm_rw1(const float* __restrict__ y2, const float* __restrict__ etot,
                           const float* __restrict__ s2sum, const float* __restrict__ s2sq,
                           const float* __restrict__ g2e, const float* __restrict__ b2e,
                           const float* __restrict__ g3, const float* __restrict__ b3,
                           const float* __restrict__ W, const float* __restrict__ bias,
                           float* __restrict__ Y,
                           float* __restrict__ osum, float* __restrict__ osq) {
    __shared__ float Xs[64][66];
    __shared__ float Ws[64][66];
    __shared__ float bsc[64], bsh[64];
    const int t = threadIdx.x;
    const int row0 = blockIdx.x * 64, cb = blockIdx.y * 64;
    const int tx = t & 15, ty = t >> 4;
    const int c0 = tx * 4, r0 = ty * 4;
    const int bb = row0 >> 12;
    if (t < 64) {
        const float iG = 1.0f / 4096.f, iNG = 1.0f / 16384.f;
        float S1 = s2sum[t], S2 = s2sq[t];
        float m2 = S1 * iG;
        float is2 = rsqrtf(S2 * iG - m2 * m2 + BNEPS);
        float sc2 = is2 * g2e[t], sh2 = b2e[t] - m2 * sc2;
        float sz = sc2 * S1 + 4096.f * sh2;
        float szz = sc2 * sc2 * S2 + 2.f * sc2 * sh2 * S1 + 4096.f * sh2 * sh2;
        float e0 = etot[t], e1 = etot[64 + t], e2 = etot[128 + t], e3 = etot[192 + t];
        float se = e0 + e1 + e2 + e3;
        float see = e0 * e0 + e1 * e1 + e2 * e2 + e3 * e3;
        float sumF = 4.f * sz + 4096.f * se;
        float sqF = 4.f * szz + 2.f * sz * se + 4096.f * see;
        float m3 = sumF * iNG;
        float is3 = rsqrtf(sqF * iNG - m3 * m3 + BNEPS);
        float eb = etot[bb * 64 + t];
        bsc[t] = sc2 * is3 * g3[t];
        bsh[t] = (sh2 + eb - m3) * is3 * g3[t] + b3[t];
    }
    __syncthreads();
    for (int i = t; i < 1024; i += 256) {
        int r = i >> 4, kq = (i & 15) * 4;
        int g = (row0 + r) & 4095;
        float4 v = *(const float4*)&y2[(size_t)g * 64 + kq];
        Xs[r][kq] = fmaxf(v.x * bsc[kq] + bsh[kq], 0.f);
        Xs[r][kq + 1] = fmaxf(v.y * bsc[kq + 1] + bsh[kq + 1], 0.f);
        Xs[r][kq + 2] = fmaxf(v.z * bsc[kq + 2] + bsh[kq + 2], 0.f);
        Xs[r][kq + 3] = fmaxf(v.w * bsc[kq + 3] + bsh[kq + 3], 0.f);
        float4 wv = *(const float4*)&W[(size_t)(cb + r) * 64 + kq];
        Ws[r][kq] = wv.x; Ws[r][kq + 1] = wv.y; Ws[r][kq + 2] = wv.z; Ws[r][kq + 3] = wv.w;
    }
    __syncthreads();
    float acc[4][4];
    #pragma unroll
    for (int j = 0; j < 4; j++)
        #pragma unroll
        for (int i = 0; i < 4; i++) acc[j][i] = 0.f;
    #pragma unroll 4
    for (int k = 0; k < 64; k += 2) {
        float2 a[4], b[4];
        #pragma unroll
        for (int j = 0; j < 4; j++) a[j] = *(const float2*)&Xs[r0 + j][k];
        #pragma unroll
        for (int i = 0; i < 4; i++) b[i] = *(const float2*)&Ws[c0 + i][k];
        #pragma unroll
        for (int j = 0; j < 4; j++)
            #pragma unroll
            for (int i = 0; i < 4; i++)
                acc[j][i] += a[j].x * b[i].x + a[j].y * b[i].y;
    }
    float4 bi = *(const float4*)&bias[cb + c0];
    float scol[4] = {0.f, 0.f, 0.f, 0.f}, qcol[4] = {0.f, 0.f, 0.f, 0.f};
    #pragma unroll
    for (int j = 0; j < 4; j++) {
        float4 o;
        o.x = acc[j][0] + bi.x; o.y = acc[j][1] + bi.y;
        o.z = acc[j][2] + bi.z; o.w = acc[j][3] + bi.w;
        *(float4*)&Y[(size_t)(row0 + r0 + j) * 128 + cb + c0] = o;
        scol[0] += o.x; scol[1] += o.y; scol[2] += o.z; scol[3] += o.w;
        qcol[0] += o.x * o.x; qcol[1] += o.y * o.y;
        qcol[2] += o.z * o.z; qcol[3] += o.w * o.w;
    }
    __syncthreads();
    #pragma unroll
    for (int i = 0; i < 4; i++) { Xs[ty][c0 + i] = scol[i]; Ws[ty][c0 + i] = qcol[i]; }
    __syncthreads();
    if (t < 64) {
        float ss = 0.f, qq = 0.f;
        #pragma unroll
        for (int r = 0; r < 16; r++) { ss += Xs[r][t]; qq += Ws[r][t]; }
        atomicAdd(&osum[cb + t], ss);
        atomicAdd(&osq[cb + t], qq);
    }
}

// ================= fused QKV gemm =================
__launch_bounds__(256)
__global__ void k_gemm_qkv(const float* __restrict__ X, const float* __restrict__ W,
                           const float* __restrict__ bias,
                           const float* __restrict__ bnsum, const float* __restrict__ bnsq,
                           const float* __restrict__ bng, const float* __restrict__ bnb,
                           ushort_t* __restrict__ Qb, ushort_t* __restrict__ Kb,
                           ushort_t* __restrict__ Vf) {
    __shared__ float Xs[64][66];
    __shared__ float Ws[64][66];
    __shared__ float bsc[64], bsh[64];
    const int t = threadIdx.x;
    const int row0 = blockIdx.x * 64, yb = blockIdx.y, cb = yb * 64;
    const int tx = t & 15, ty = t >> 4;
    const int c0 = tx * 4, r0 = ty * 4;
    const float invN = 1.0f / (float)(BB * GG);
    if (t < 64) {
        float m = bnsum[t] * invN;
        float is_ = rsqrtf(bnsq[t] * invN - m * m + BNEPS);
        float sc = is_ * bng[t];
        bsc[t] = sc; bsh[t] = bnb[t] - m * sc;
    }
    __syncthreads();
    for (int i = t; i < 1024; i += 256) {
        int r = i >> 4, kq = (i & 15) * 4;
        float4 v = *(const float4*)&X[(size_t)(row0 + r) * 64 + kq];
        Xs[r][kq] = v.x * bsc[kq] + bsh[kq];
        Xs[r][kq + 1] = v.y * bsc[kq + 1] + bsh[kq + 1];
        Xs[r][kq + 2] = v.z * bsc[kq + 2] + bsh[kq + 2];
        Xs[r][kq + 3] = v.w * bsc[kq + 3] + bsh[kq + 3];
        float4 wv = *(const float4*)&W[(size_t)(cb + r) * 64 + kq];
        Ws[r][kq] = wv.x; Ws[r][kq + 1] = wv.y; Ws[r][kq + 2] = wv.z; Ws[r][kq + 3] = wv.w;
    }
    __syncthreads();
    float acc[4][4];
    #pragma unroll
    for (int j = 0; j < 4; j++)
        #pragma unroll
        for (int i = 0; i < 4; i++) acc[j][i] = 0.f;
    #pragma unroll 4
    for (int k = 0; k < 64; k += 2) {
        float2 a[4], b[4];
        #pragma unroll
        for (int j = 0; j < 4; j++) a[j] = *(const float2*)&Xs[r0 + j][k];
        #pragma unroll
        for (int i = 0; i < 4; i++) b[i] = *(const float2*)&Ws[c0 + i][k];
        #pragma unroll
        for (int j = 0; j < 4; j++)
            #pragma unroll
            for (int i = 0; i < 4; i++)
                acc[j][i] += a[j].x * b[i].x + a[j].y * b[i].y;
    }
    float4 bi = *(const float4*)&bias[cb + c0];
    const int b2 = row0 >> 12, tile = (row0 & 4095) >> 6;
    if (yb < 2) {
        ushort_t* Dst = (yb == 0) ? Qb : Kb;
        const float sc2 = (yb == 0) ? QPRE : 1.0f;
        const int h = c0 >> 5, d = c0 & 31;
        #pragma unroll
        for (int j = 0; j < 4; j++) {
            union { ushort_t u[4]; uint2 v; } pk;
            pk.u[0] = f2b((acc[j][0] + bi.x) * sc2);
            pk.u[1] = f2b((acc[j][1] + bi.y) * sc2);
            pk.u[2] = f2b((acc[j][2] + bi.z) * sc2);
            pk.u[3] = f2b((acc[j][3] + bi.w) * sc2);
            int g = (row0 & 4095) + r0 + j;
            *(uint2*)&Dst[((size_t)(b2 * 2 + h) * GG + g) * 32 + d] = pk.v;
        }
    } else {
        __syncthreads();
        #pragma unroll
        for (int j = 0; j < 4; j++) {
            Xs[r0 + j][c0] = acc[j][0] + bi.x;
            Xs[r0 + j][c0 + 1] = acc[j][1] + bi.y;
            Xs[r0 + j][c0 + 2] = acc[j][2] + bi.z;
            Xs[r0 + j][c0 + 3] = acc[j][3] + bi.w;
        }
        __syncthreads();
        #pragma unroll
        for (int h = 0; h < 2; h++) {
            union { ushort_t u[8]; uint4 v; } pk;
            #pragma unroll
            for (int j = 0; j < 8; j++) {
                int idx = t * 8 + j;
                int g2 = idx >> 8, L = (idx >> 2) & 63, i = idx & 3;
                int key = (g2 >> 1) * 16 + ((L >> 4) << 2) + i;
                int d = ((g2 & 1) << 4) + (L & 15);
                pk.u[j] = f2b(Xs[key][h * 32 + d]);
            }
            *(uint4*)&Vf[((size_t)((b2 * 2 + h) * 64 + tile)) * 2048 + t * 8] = pk.v;
        }
    }
}

// ---- MFMA flash attention, 2-bh per block, 128-key tiles, 2-way split-k ----
// partials stored bf16
__launch_bounds__(512, 4)
__global__ void k_attn_mfma(const ushort_t* __restrict__ Qb, const ushort_t* __restrict__ Kb,
                            const ushort_t* __restrict__ Vf, const float* __restrict__ mask,
                            const float* __restrict__ mflag,
                            ushort_t* __restrict__ opA, ushort_t* __restrict__ opB,
                            float* __restrict__ Lp) {
    __shared__ ushort_t Kl[2][2][4096];   // 2buf x 2bh x (128 keys x 32 d)
    __shared__ ushort_t Vl[2][2][4096];
    const int split = blockIdx.y;
    const int bh0 = blockIdx.z * 2;
    const int q0 = blockIdx.x * 64;
    const int kstart = split * (GG / 2), kend = kstart + (GG / 2);
    const int t = threadIdx.x;
    const int lane = t & 63, w = t >> 6;
    const int qg = w >> 1, kh = w & 1;
    const int l15 = lane & 15, quad = lane >> 4;
    const int um = (*(const int*)mflag) != 0;   // wave-uniform

    sh8 qf[2];
    #pragma unroll
    for (int bh = 0; bh < 2; bh++)
        qf[bh] = *(const sh8*)&Qb[((size_t)(bh0 + bh) * GG + q0 + qg * 16 + l15) * 32 + quad * 8];
    const float* mrow = mask + (size_t)(q0 + qg * 16 + l15) * GG + quad * 4;

    auto stage = [&](int buf, int k0) {
        int bh = t >> 8, c = t & 255;     // 512 threads: 2bh x 256 chunks per 64-key half
        int key = ((c >> 6) << 4) + (c & 15);
        int chunk = (c >> 4) & 3;
        #pragma unroll
        for (int s = 0; s < 2; s++) {
            gld16(Kb + ((size_t)(bh0 + bh) * GG + k0 + s * 64 + key) * 32 + chunk * 8,
                  &Kl[buf][bh][s * 2048 + c * 8]);
            gld16(Vf + ((size_t)((bh0 + bh) * 64 + (k0 >> 6) + s)) * 2048 + c * 8,
                  &Vl[buf][bh][s * 2048 + c * 8]);
        }
    };
    stage(0, kstart);

    f4 O0[2], O1[2];
    float ls[2];
    #pragma unroll
    for (int bh = 0; bh < 2; bh++) {
        O0[bh] = f4{0.f, 0.f, 0.f, 0.f};
        O1[bh] = f4{0.f, 0.f, 0.f, 0.f};
        ls[bh] = 0.f;
    }

    auto run = [&](auto tag) {
        constexpr bool U = decltype(tag)::v;
        for (int k0 = kstart; k0 < kend; k0 += 128) {
            const int cur = ((k0 - kstart) >> 7) & 1;
            __syncthreads();
            if (k0 + 128 < kend) stage(cur ^ 1, k0 + 128);
            #pragma unroll
            for (int bh = 0; bh < 2; bh++) {
                #pragma unroll
                for (int ii = 0; ii < 4; ii++) {
                    const int i2 = kh * 4 + ii;
                    sh8 kf = *(const sh8*)&Kl[cur][bh][(i2 * 64 + lane) * 8];
                    f4 z = {0.f, 0.f, 0.f, 0.f};
                    f4 sa = __builtin_amdgcn_mfma_f32_16x16x32_bf16(kf, qf[bh], z, 0, 0, 0);
                    float p0, p1, p2, p3;
                    if constexpr (U) {
                        float4 mv = *(const float4*)&mrow[k0 + i2 * 16];
                        p0 = exp2f(fmaf(mv.x, LOG2E, sa[0]));
                        p1 = exp2f(fmaf(mv.y, LOG2E, sa[1]));
                        p2 = exp2f(fmaf(mv.z, LOG2E, sa[2]));
                        p3 = exp2f(fmaf(mv.w, LOG2E, sa[3]));
                    } else {
                        p0 = exp2f(sa[0]); p1 = exp2f(sa[1]);
                        p2 = exp2f(sa[2]); p3 = exp2f(sa[3]);
                    }
                    ls[bh] += (p0 + p1) + (p2 + p3);
                    // truncation pack f32->bf16 (round-toward-zero): P in (0,1],
                    // rel err <= 2^-8 on numerator only; well within threshold.
                    uint_t a0 = __builtin_bit_cast(uint_t, p0);
                    uint_t a1 = __builtin_bit_cast(uint_t, p1);
                    uint_t a2 = __builtin_bit_cast(uint_t, p2);
                    uint_t a3 = __builtin_bit_cast(uint_t, p3);
                    union { uint_t u[2]; sh4 v; } pkp;
                    pkp.u[0] = (a0 >> 16) | (a1 & 0xFFFF0000u);
                    pkp.u[1] = (a2 >> 16) | (a3 & 0xFFFF0000u);
                    sh4 vf0 = *(const sh4*)&Vl[cur][bh][((i2 * 2 + 0) * 64 + lane) * 4];
                    sh4 vf1 = *(const sh4*)&Vl[cur][bh][((i2 * 2 + 1) * 64 + lane) * 4];
                    O0[bh] = MFMA16(pkp.v, vf0, O0[bh]);
                    O1[bh] = MFMA16(pkp.v, vf1, O1[bh]);
                }
            }
        }
    };
    if (um) run(MaskOn{}); else run(MaskOff{});

    #pragma unroll
    for (int bh = 0; bh < 2; bh++) {
        ls[bh] += __shfl_xor(ls[bh], 16, 64);
        ls[bh] += __shfl_xor(ls[bh], 32, 64);
    }
    __syncthreads();
    float* Ox = (float*)&Kl[0][0][0];   // 2*64*32 floats = 16 KB (fits in Kl's 32 KB)
    float* Lx = (float*)&Vl[0][0][0];
    if (kh == 0) {
        #pragma unroll
        for (int bh = 0; bh < 2; bh++) {
            #pragma unroll
            for (int r = 0; r < 4; r++) {
                int ql = qg * 16 + quad * 4 + r;
                Ox[(bh * 64 + ql) * 32 + l15] = O0[bh][r];
                Ox[(bh * 64 + ql) * 32 + l15 + 16] = O1[bh][r];
            }
            if (quad == 0) Lx[bh * 64 + qg * 16 + l15] = ls[bh];
        }
    }
    __syncthreads();
    if (kh == 1) {
        ushort_t* op = (split == 0) ? opA : opB;
        #pragma unroll
        for (int bh = 0; bh < 2; bh++) {
            int gbh = bh0 + bh;
            #pragma unroll
            for (int r = 0; r < 4; r++) {
                int ql = qg * 16 + quad * 4 + r;
                size_t o = ((size_t)gbh * GG + q0 + ql) * 32 + l15;
                op[o] = f2b(O0[bh][r] + Ox[(bh * 64 + ql) * 32 + l15]);
                op[o + 16] = f2b(O1[bh][r] + Ox[(bh * 64 + ql) * 32 + l15 + 16]);
            }
            if (quad == 0)
                Lp[split * 32768 + gbh * GG + q0 + qg * 16 + l15] =
                    ls[bh] + Lx[bh * 64 + qg * 16 + l15];
        }
    }
}

// ===== k_comb: split-k combine + attn-out gemm + LN1 -> h1 bf16 (1024 blocks x 16 rows) =====
__launch_bounds__(256)
__global__ void k_comb(const ushort_t* __restrict__ opA, const ushort_t* __restrict__ opB,
                       const float* __restrict__ Lp, const float* __restrict__ yrw2,
                       const float* __restrict__ Waout, const float* __restrict__ baout,
                       const float* __restrict__ bsum5, const float* __restrict__ bsq5,
                       const float* __restrict__ bg5, const float* __restrict__ bb5,
                       const float* __restrict__ lg1, const float* __restrict__ lb1,
                       ushort_t* __restrict__ h1out) {
    __shared__ float Wt[4160];     // aout_w^T [64][65]
    __shared__ float Cs[1040];     // ctx [16][65]
    const int t = threadIdx.x;
    const int r0b = blockIdx.x * 16;
    const int lane = t & 63, w = t >> 6;
    for (int i = t; i < 4096; i += 256) Wt[(i & 63) * 65 + (i >> 6)] = Waout[i];
    {
        int col = t & 63, rl = t >> 6;
        int hh = col >> 5, d = col & 31;
        #pragma unroll
        for (int jj = 0; jj < 4; jj++) {
            int lrow = rl * 4 + jj;
            int row = r0b + lrow;
            int b = row >> 12, q = row & 4095;
            int bhq = (b * 2 + hh) * GG + q;
            size_t oi = (size_t)bhq * 32 + d;
            float num = b2f32(opA[oi]) + b2f32(opB[oi]);
            float den = Lp[bhq] + Lp[32768 + bhq];
            Cs[lrow * 65 + col] = num / den;
        }
    }
    __syncthreads();
    const float invN = 1.0f / (float)(BB * GG);
    float m5 = bsum5[lane] * invN;
    float is5 = rsqrtf(bsq5[lane] * invN - m5 * m5 + BNEPS);
    #pragma unroll
    for (int j = 0; j < 4; j++) {
        int lrow = w * 4 + j;
        int row = r0b + lrow;
        float acc = baout[lane];
        const float* cr = Cs + lrow * 65;
        #pragma unroll 8
        for (int k = 0; k < 64; k++) acc += cr[k] * Wt[k * 65 + lane];
        float ov = (yrw2[(size_t)row * 64 + lane] - m5) * is5 * bg5[lane] + bb5[lane];
        float v = ov + acc;
        float s = v;
        for (int o = 32; o > 0; o >>= 1) s += __shfl_xor(s, o, 64);
        float mean = s * (1.f / 64.f);
        float d = v - mean;
        float sq = d * d;
        for (int o = 32; o > 0; o >>= 1) sq += __shfl_xor(sq, o, 64);
        float inv = rsqrtf(sq * (1.f / 64.f) + BNEPS);
        h1out[(size_t)row * 64 + lane] = f2b(d * inv * lg1[lane] + lb1[lane]);
    }
}

// ===== k_ffn: FFN1 + FFN2 + LN2 + heads (256 blocks x 64 rows), h1 bf16 from global =====
__launch_bounds__(256)
__global__ void k_ffn(const ushort_t* __restrict__ h1b,
                      const ushort_t* __restrict__ W1b, const float* __restrict__ b1f,
                      const ushort_t* __restrict__ W2b, const float* __restrict__ b2f,
                      const float* __restrict__ lg2, const float* __restrict__ lb2,
                      const float* __restrict__ indvw, const float* __restrict__ indvb,
                      const float* __restrict__ hdc, const float* __restrict__ d2w,
                      const float* __restrict__ d2b, const float* __restrict__ x,
                      float* __restrict__ outp) {
    __shared__ ushort_t Hb[4096];   // h1 bf16 frags
    __shared__ ushort_t FT[32768];  // fft tile [w][16][64][8]
    __shared__ ushort_t WS[2][4096];
    const int t = threadIdx.x;
    const int r0b = blockIdx.x * 64;
    const int lane = t & 63, w = t >> 6;
    const int l15 = lane & 15, quad = lane >> 4;

    // copy h1 bf16 frags from global (already bf16 -> pure copy)
    if (t < 128) {
        int kt = t >> 6, lane6 = t & 63;
        int q2 = (lane6 >> 4) & 3, r15 = lane6 & 15;
        for (int rg = 0; rg < 4; rg++) {
            uint4 v4 = *(const uint4*)&h1b[(size_t)(r0b + rg * 16 + r15) * 64 + kt * 32 + q2 * 8];
            *(uint4*)&Hb[(rg * 2 + kt) * 512 + lane6 * 8] = v4;
        }
    }
    // FFN1: 8 colblocks, double-buffered weight staging
    auto stage1 = [&](int buf, int cb8) {
        int cb = cb8 * 64;
        #pragma unroll
        for (int kt = 0; kt < 2; kt++)
            gld16(W1b + (size_t)((cb + w * 16 + l15) * 64 + kt * 32 + quad * 8),
                  &WS[buf][(w * 2 + kt) * 512 + lane * 8]);
    };
    stage1(0, 0);
    for (int cb8 = 0; cb8 < 8; cb8++) {
        const int cur = cb8 & 1;
        __syncthreads();           // WS[cur] DMA done (+ Hb writes on first iter)
        if (cb8 + 1 < 8) stage1(cur ^ 1, cb8 + 1);
        sh8 xf0 = *(const sh8*)&Hb[(w * 2 + 0) * 512 + lane * 8];
        sh8 xf1 = *(const sh8*)&Hb[(w * 2 + 1) * 512 + lane * 8];
        const int cb = cb8 * 64;
        #pragma unroll
        for (int c = 0; c < 4; c++) {
            sh8 wf0 = *(const sh8*)&WS[cur][(c * 2 + 0) * 512 + lane * 8];
            sh8 wf1 = *(const sh8*)&WS[cur][(c * 2 + 1) * 512 + lane * 8];
            f4 z = {0.f, 0.f, 0.f, 0.f};
            f4 acc = __builtin_amdgcn_mfma_f32_16x16x32_bf16(wf0, xf0, z, 0, 0, 0);
            acc = __builtin_amdgcn_mfma_f32_16x16x32_bf16(wf1, xf1, acc, 0, 0, 0);
            float4 bv = *(const float4*)&b1f[cb + c * 16 + quad * 4];
            union { ushort_t u[4]; uint2 v2; } pk;
            pk.u[0] = f2b(fmaxf(acc[0] + bv.x, 0.f));
            pk.u[1] = f2b(fmaxf(acc[1] + bv.y, 0.f));
            pk.u[2] = f2b(fmaxf(acc[2] + bv.z, 0.f));
            pk.u[3] = f2b(fmaxf(acc[3] + bv.w, 0.f));
            int kt512 = cb8 * 2 + (c >> 1);
            int quadp = (c & 1) * 2 + (quad >> 1);
            int j0 = (quad & 1) * 4;
            *(uint2*)&FT[((w * 16 + kt512) * 64 + quadp * 16 + l15) * 8 + j0] = pk.v2;
        }
    }
    // FFN2: K=512, double-buffered weight staging, x-frags from FT
    auto stage2 = [&](int buf, int k0) {
        #pragma unroll
        for (int kt = 0; kt < 2; kt++)
            gld16(W2b + (size_t)((w * 16 + l15) * 512 + k0 + kt * 32 + quad * 8),
                  &WS[buf][(w * 2 + kt) * 512 + lane * 8]);
    };
    stage2(0, 0);
    f4 acc2[4];
    #pragma unroll
    for (int c = 0; c < 4; c++) acc2[c] = f4{0.f, 0.f, 0.f, 0.f};
    for (int k0 = 0; k0 < 512; k0 += 64) {
        const int cur = (k0 >> 6) & 1;
        __syncthreads();           // WS[cur] DMA done + (first iter) FT writes visible
        if (k0 + 64 < 512) stage2(cur ^ 1, k0 + 64);
        const int ktb = k0 >> 5;
        #pragma unroll
        for (int kt = 0; kt < 2; kt++) {
            sh8 xf = *(const sh8*)&FT[((w * 16 + ktb + kt) * 64 + lane) * 8];
            #pragma unroll
            for (int c = 0; c < 4; c++) {
                sh8 wf = *(const sh8*)&WS[cur][(c * 2 + kt) * 512 + lane * 8];
                acc2[c] = __builtin_amdgcn_mfma_f32_16x16x32_bf16(wf, xf, acc2[c], 0, 0, 0);
            }
        }
    }
    // epilogue: LN2 + per-gene head + recon
    const int row = r0b + w * 16 + l15;
    const int b = row >> 12, g = row & 4095;
    float v[4][4];
    float s = 0.f, sq = 0.f;
    #pragma unroll
    for (int c = 0; c < 4; c++) {
        float4 bv = *(const float4*)&b2f[c * 16 + quad * 4];
        uint2 hraw = *(const uint2*)&h1b[(size_t)row * 64 + c * 16 + quad * 4];
        ushort_t hu[4];
        hu[0] = (ushort_t)(hraw.x & 0xFFFFu); hu[1] = (ushort_t)(hraw.x >> 16);
        hu[2] = (ushort_t)(hraw.y & 0xFFFFu); hu[3] = (ushort_t)(hraw.y >> 16);
        #pragma unroll
        for (int i = 0; i < 4; i++) {
            float hv = b2f32(hu[i]);
            float bvi = (i == 0) ? bv.x : (i == 1) ? bv.y : (i == 2) ? bv.z : bv.w;
            v[c][i] = hv + acc2[c][i] + bvi;
            s += v[c][i]; sq += v[c][i] * v[c][i];
        }
    }
    s += __shfl_xor(s, 16, 64);  s += __shfl_xor(s, 32, 64);
    sq += __shfl_xor(sq, 16, 64); sq += __shfl_xor(sq, 32, 64);
    float mean = s * (1.f / 64.f);
    float inv = rsqrtf(sq * (1.f / 64.f) - mean * mean + BNEPS);
    float pd = 0.f;
    #pragma unroll
    for (int c = 0; c < 4; c++) {
        float4 lgv = *(const float4*)&lg2[c * 16 + quad * 4];
        float4 lbv = *(const float4*)&lb2[c * 16 + quad * 4];
        float4 iwv = *(const float4*)&indvw[(size_t)g * 64 + c * 16 + quad * 4];
        pd += ((v[c][0] - mean) * inv * lgv.x + lbv.x) * iwv.x;
        pd += ((v[c][1] - mean) * inv * lgv.y + lbv.y) * iwv.y;
        pd += ((v[c][2] - mean) * inv * lgv.z + lbv.z) * iwv.z;
        pd += ((v[c][3] - mean) * inv * lgv.w + lbv.w) * iwv.w;
    }
    float rc = 0.f;
    #pragma unroll
    for (int i = 0; i < 8; i++)
        rc += hdc[b * 32 + quad * 8 + i] * d2w[(size_t)g * 32 + quad * 8 + i];
    pd += __shfl_xor(pd, 16, 64); pd += __shfl_xor(pd, 32, 64);
    rc += __shfl_xor(rc, 16, 64); rc += __shfl_xor(rc, 32, 64);
    if (quad == 0) {
        float recon = rc + d2b[g];
        if (x[row] == 0.f) recon = 0.f;
        outp[row] = pd + indvb[g] + recon;
    }
}

extern "C" void kernel_launch(void* const* d_in, const int* in_sizes, int n_in,
                              void* d_out, int out_size, void* d_ws, size_t ws_size,
                              hipStream_t stream) {
    const float* x        = (const float*)d_in[0];
    const int*   pert_idx = (const int*)  d_in[1];
    const float* mask     = (const float*)d_in[2];
    const int*   ei_co    = (const int*)  d_in[3];
    const float* w_co     = (const float*)d_in[4];
    const int*   ei_go    = (const int*)  d_in[5];
    const float* w_go     = (const float*)d_in[6];
    const float* gene_emb = (const float*)d_in[7];
    const float* emb_pos  = (const float*)d_in[8];
    const float* pert_tbl = (const float*)d_in[9];
    const float* sg_co_w  = (const float*)d_in[10];
    const float* sg_co_b  = (const float*)d_in[11];
    const float* sg_go_w  = (const float*)d_in[12];
    const float* sg_go_b  = (const float*)d_in[13];
    const float* bn_emb_g = (const float*)d_in[14];
    const float* bn_emb_b = (const float*)d_in[15];
    const float* etv1_w   = (const float*)d_in[16];
    const float* etv1_b   = (const float*)d_in[17];
    const float* etv1_g   = (const float*)d_in[18];
    const float* etv1_be  = (const float*)d_in[19];
    const float* etv2_w   = (const float*)d_in[20];
    const float* etv2_b   = (const float*)d_in[21];
    const float* etv2_g   = (const float*)d_in[22];
    const float* etv2_be  = (const float*)d_in[23];
    const float* pf1_w    = (const float*)d_in[24];
    const float* pf1_b    = (const float*)d_in[25];
    const float* pf1_g    = (const float*)d_in[26];
    const float* pf1_be   = (const float*)d_in[27];
    const float* pf2_w    = (const float*)d_in[28];
    const float* pf2_b    = (const float*)d_in[29];
    const float* pf2_g    = (const float*)d_in[30];
    const float* pf2_be   = (const float*)d_in[31];
    const float* rw1_w    = (const float*)d_in[32];
    const float* rw1_b    = (const float*)d_in[33];
    const float* rw1_g    = (const float*)d_in[34];
    const float* rw1_be   = (const float*)d_in[35];
    const float* rw2_w    = (const float*)d_in[36];
    const float* rw2_b    = (const float*)d_in[37];
    const float* rw2_g    = (const float*)d_in[38];
    const float* rw2_be   = (const float*)d_in[39];
    const float* bnpb_g   = (const float*)d_in[40];
    const float* bnpb_b   = (const float*)d_in[41];
    const float* ain_w    = (const float*)d_in[42];
    const float* ain_b    = (const float*)d_in[43];
    const float* aout_w   = (const float*)d_in[44];
    const float* aout_b   = (const float*)d_in[45];
    const float* ln1_g    = (const float*)d_in[46];
    const float* ln1_b    = (const float*)d_in[47];
    const float* ff1_w    = (const float*)d_in[48];
    const float* ff1_b    = (const float*)d_in[49];
    const float* ff2_w    = (const float*)d_in[50];
    const float* ff2_b    = (const float*)d_in[51];
    const float* ln2_g    = (const float*)d_in[52];
    const float* ln2_b    = (const float*)d_in[53];
    const float* indv_w   = (const float*)d_in[54];
    const float* indv_b   = (const float*)d_in[55];
    const float* ve1_w    = (const float*)d_in[56];
    const float* ve1_b    = (const float*)d_in[57];
    const float* vmu_w    = (const float*)d_in[58];
    const float* vmu_b    = (const float*)d_in[59];
    const float* vlv_w    = (const float*)d_in[60];
    const float* vlv_b    = (const float*)d_in[61];
    const float* vd1_w    = (const float*)d_in[62];
    const float* vd1_b    = (const float*)d_in[63];
    const float* vd2_w    = (const float*)d_in[64];
    const float* vd2_b    = (const float*)d_in[65];
    const float* veps     = (const float*)d_in[66];

    float* ws   = (float*)d_ws;
    float* outp = (float*)d_out;

    float* stm1 = ws + OF_STATS + 1 * 256; float* sti1 = stm1 + 128;
    float* stm2 = ws + OF_STATS + 2 * 256; float* sti2 = stm2 + 128;
    float* stm4 = ws + OF_STATS + 4 * 256; float* sti4 = stm4 + 128;
    float* stm5 = ws + OF_STATS + 5 * 256; float* sti5 = stm5 + 128;

    float* basein = ws + OF_BASEIN;
    float* y1     = ws + OF_Y1;
    float* y2     = ws + OF_Y2;
    float* yrw1   = ws + OF_RW1;
    float* yrw2   = ws + OF_RW2;
    ushort_t* opA = (ushort_t*)(ws + OF_OPA);
    ushort_t* opB = (ushort_t*)(ws + OF_OPB);
    float* Lp     = ws + OF_LP;
    ushort_t* h1buf = (ushort_t*)(ws + OF_H1);
    ushort_t* Qb  = (ushort_t*)(ws + OF_QB);
    ushort_t* Kb  = (ushort_t*)(ws + OF_KB);
    ushort_t* Vf  = (ushort_t*)(ws + OF_VF);
    ushort_t* W1b = (ushort_t*)(ws + OF_W1B);
    ushort_t* W2b = (ushort_t*)(ws + OF_W2B);

    const int NG = BB * GG; // 16384
    const float iG = 1.0f / (float)GG, iNG = 1.0f / (float)NG;

    // zero stats+deg+pslot+etot/hdc/he+mflag (contiguous) and edge-count histogram
    hipMemsetAsync(ws, 0, 11268 * sizeof(float), stream);
    hipMemsetAsync(ws + OF_CNT, 0, 4096 * sizeof(int), stream);

    // K12: degrees + co edge counts, gene_emb stats, vae_he, FFN weight->bf16, mask scan
    k_fat12<<<1792, 256, 0, stream>>>(ws, ei_co, w_co, ei_go, w_go, gene_emb,
                                      x, ve1_w, ve1_b, ff1_w, ff2_w, mask);
    // CSR offsets for co edges
    k_scan<<<1, 256, 0, stream>>>(ws);
    // K3: edge scatter (CSR sort) + pert edge scan + vae_mid
    k_fat3<<<641, 256, 0, stream>>>(ws, ei_co, w_co, pert_idx,
                                    ei_go, w_go, pert_tbl,
                                    vmu_w, vmu_b, vlv_w, vlv_b, vd1_w, vd1_b,
                                    veps, outp + NG);
    // K4: base_combine (fused CSR gather) + pert MLP
    k_fat4<<<1025, 256, 0, stream>>>(ws, gene_emb, emb_pos, sg_co_w, sg_co_b,
                                     bn_emb_g, bn_emb_b, pert_idx, pert_tbl,
                                     sg_go_w, sg_go_b,
                                     pf1_w, pf1_b, pf1_g, pf1_be,
                                     pf2_w, pf2_b, pf2_g, pf2_be);
    // etv MLP
    k_gemm64<<<dim3(GG / 64, 1), 256, 0, stream>>>(basein, etv1_w, etv1_b, y1, 64, 64,
                                                   nullptr, nullptr, nullptr, nullptr, 0.f, 0,
                                                   stm1, sti1);
    k_gemm64<<<dim3(GG / 64, 1), 256, 0, stream>>>(y1, etv2_w, etv2_b, y2, 64, 64,
                                                   stm1, sti1, etv1_g, etv1_be, iG, 1,
                                                   stm2, sti2);
    // rw MLP (analytic flat stats; no flatpre)
    k_gemm_rw1<<<dim3(NG / 64, 2), 256, 0, stream>>>(y2, ws + OF_ETOT, stm2, sti2,
                                                     etv2_g, etv2_be, bnpb_g, bnpb_b,
                                                     rw1_w, rw1_b, yrw1, stm4, sti4);
    k_gemm64<<<dim3(NG / 64, 1), 256, 0, stream>>>(yrw1, rw2_w, rw2_b, yrw2, 128, 64,
                                                   stm4, sti4, rw1_g, rw1_be, iNG, 1,
                                                   stm5, sti5);
    // transformer
    k_gemm_qkv<<<dim3(NG / 64, 3), 256, 0, stream>>>(yrw2, ain_w, ain_b,
                                                     stm5, sti5, rw2_g, rw2_be,
                                                     Qb, Kb, Vf);
    k_attn_mfma<<<dim3(GG / 64, 2, 4), 512, 0, stream>>>(Qb, Kb, Vf, mask,
                                                         ws + OF_MFLAG, opA, opB, Lp);
    // combine + attn-out + LN1 (wide grid, high occupancy) -> h1 bf16
    k_comb<<<NG / 16, 256, 0, stream>>>(opA, opB, Lp, yrw2, aout_w, aout_b,
                                        stm5, sti5, rw2_g, rw2_be, ln1_g, ln1_b, h1buf);
    // FFN + LN2 + heads
    k_ffn<<<NG / 64, 256, 0, stream>>>(h1buf, W1b, ff1_b, W2b, ff2_b, ln2_g, ln2_b,
                                       indv_w, indv_b, ws + OF_HDC, vd2_w, vd2_b,
                                       x, outp);
}